// Round 1
// baseline (1917.781 us; speedup 1.0000x reference)
//
#include <hip/hip_runtime.h>
#include <cfloat>
#include <cmath>

#define D 128
#define N_ATOMS 200000
#define E_ATOMS 800000
#define G_GROUPS 2000
#define N_BIG 7000
#define E_BIG 200000

static inline int ceil_div(int a, int b) { return (a + b - 1) / b; }

// ---------------- CSR build ----------------
__global__ void count_kernel(const int* __restrict__ dst, int* __restrict__ deg, int E) {
  int i = blockIdx.x * 256 + threadIdx.x;
  if (i < E) atomicAdd(&deg[dst[i]], 1);
}

__global__ void fill_kernel(const int* __restrict__ src, const int* __restrict__ dst,
                            const int* __restrict__ rp, int* __restrict__ fill,
                            int* __restrict__ cs, int E) {
  int i = blockIdx.x * 256 + threadIdx.x;
  if (i < E) {
    int d = dst[i];
    int pos = rp[d] + atomicAdd(&fill[d], 1);
    cs[pos] = src[i];
  }
}

// 3-phase exclusive scan (1024 elements per block in phase 1)
__global__ __launch_bounds__(256) void scan_phase1(const int* __restrict__ in, int* __restrict__ out,
                                                   int* __restrict__ bsums, int n) {
  __shared__ int lds[256];
  int t = threadIdx.x;
  int base = blockIdx.x * 1024;
  int v[4];
  int s = 0;
#pragma unroll
  for (int j = 0; j < 4; ++j) {
    int i = base + t * 4 + j;
    v[j] = (i < n) ? in[i] : 0;
    s += v[j];
  }
  lds[t] = s;
  __syncthreads();
  for (int off = 1; off < 256; off <<= 1) {
    int x = (t >= off) ? lds[t - off] : 0;
    __syncthreads();
    lds[t] += x;
    __syncthreads();
  }
  int excl = lds[t] - s;
  if (t == 255) bsums[blockIdx.x] = lds[255];
  int run = excl;
#pragma unroll
  for (int j = 0; j < 4; ++j) {
    int i = base + t * 4 + j;
    if (i < n) out[i] = run;
    run += v[j];
  }
}

__global__ __launch_bounds__(256) void scan_phase2(int* __restrict__ bsums, int* __restrict__ total_out, int nb) {
  __shared__ int lds[256];
  int t = threadIdx.x;
  int s = (t < nb) ? bsums[t] : 0;
  lds[t] = s;
  __syncthreads();
  for (int off = 1; off < 256; off <<= 1) {
    int x = (t >= off) ? lds[t - off] : 0;
    __syncthreads();
    lds[t] += x;
    __syncthreads();
  }
  if (t < nb) bsums[t] = lds[t] - s;
  if (t == 255) total_out[0] = lds[255];
}

__global__ void scan_phase3(int* __restrict__ out, const int* __restrict__ bsums, int n) {
  int i = blockIdx.x * 256 + threadIdx.x;
  if (i < n) out[i] += bsums[i >> 10];
}

// ---------------- dense ops ----------------
// Y[M,128] = X[M,128] @ W[128,128], W staged in LDS, 64 rows/block, 8x4 per thread
__global__ __launch_bounds__(256) void gemm_k128(const float* __restrict__ X, const float* __restrict__ W,
                                                 float* __restrict__ Y, int M) {
  __shared__ float Wl[128 * 128];
  int t = threadIdx.x;
  {
    const float4* W4 = (const float4*)W;
    float4* Wl4 = (float4*)Wl;
#pragma unroll
    for (int i = 0; i < 16; ++i) Wl4[t + i * 256] = W4[t + i * 256];
  }
  __syncthreads();
  int rg = t >> 5, cg = t & 31;
  int row0 = blockIdx.x * 64 + rg * 8;
  int c0 = cg * 4;
  float acc[8][4];
#pragma unroll
  for (int r = 0; r < 8; ++r) {
    acc[r][0] = 0.f; acc[r][1] = 0.f; acc[r][2] = 0.f; acc[r][3] = 0.f;
  }
  for (int k = 0; k < 128; k += 4) {
    float4 xr[8];
#pragma unroll
    for (int r = 0; r < 8; ++r) {
      int row = row0 + r;
      xr[r] = (row < M) ? *(const float4*)(X + (size_t)row * D + k) : make_float4(0.f, 0.f, 0.f, 0.f);
    }
#pragma unroll
    for (int kk = 0; kk < 4; ++kk) {
      float4 wv = *(const float4*)(&Wl[(k + kk) * 128 + c0]);
#pragma unroll
      for (int r = 0; r < 8; ++r) {
        float a = (kk == 0) ? xr[r].x : (kk == 1) ? xr[r].y : (kk == 2) ? xr[r].z : xr[r].w;
        acc[r][0] = fmaf(a, wv.x, acc[r][0]);
        acc[r][1] = fmaf(a, wv.y, acc[r][1]);
        acc[r][2] = fmaf(a, wv.z, acc[r][2]);
        acc[r][3] = fmaf(a, wv.w, acc[r][3]);
      }
    }
  }
#pragma unroll
  for (int r = 0; r < 8; ++r) {
    int row = row0 + r;
    if (row < M) *(float4*)(Y + (size_t)row * D + c0) = make_float4(acc[r][0], acc[r][1], acc[r][2], acc[r][3]);
  }
}

// hs[i] = h[i].attS ; hd[i] = h[i].attD  (one wave per row)
__global__ void row_dots(const float* __restrict__ H, const float* __restrict__ aS, const float* __restrict__ aD,
                         float* __restrict__ hs, float* __restrict__ hd, int M) {
  int gid = blockIdx.x * blockDim.x + threadIdx.x;
  int row = gid >> 6;
  int lane = threadIdx.x & 63;
  if (row >= M) return;
  float2 hv = ((const float2*)(H + (size_t)row * D))[lane];
  float2 s2 = ((const float2*)aS)[lane];
  float2 d2 = ((const float2*)aD)[lane];
  float ps = hv.x * s2.x + hv.y * s2.y;
  float pd = hv.x * d2.x + hv.y * d2.y;
  for (int off = 32; off; off >>= 1) {
    ps += __shfl_xor(ps, off);
    pd += __shfl_xor(pd, off);
  }
  if (lane == 0) { hs[row] = ps; hd[row] = pd; }
}

__global__ void pnorm_kernel(const float* __restrict__ p, float* __restrict__ pn) {
  int t = threadIdx.x;  // 64
  float2 v = ((const float2*)p)[t];
  float s = v.x * v.x + v.y * v.y;
  for (int off = 32; off; off >>= 1) s += __shfl_xor(s, off);
  if (t == 0) pn[0] = sqrtf(s);
}

// per-destination GAT softmax + weighted aggregation + bias + relu + topk gate (one wave per dst)
__global__ __launch_bounds__(256) void gat_aggr(const float* __restrict__ H, const float* __restrict__ hs,
                                                const float* __restrict__ hd, const int* __restrict__ rp,
                                                const int* __restrict__ cs, const float* __restrict__ bias,
                                                const float* __restrict__ poolP, const float* __restrict__ pn,
                                                float* __restrict__ Xout, int N) {
  int gid = blockIdx.x * blockDim.x + threadIdx.x;
  int d = gid >> 6;
  int lane = threadIdx.x & 63;
  if (d >= N) return;
  int beg = rp[d], end = rp[d + 1];
  float hdd = hd[d];
  float eself = hs[d] + hdd;
  eself = (eself >= 0.f) ? eself : 0.2f * eself;
  // max
  float mloc = eself;
  for (int i = beg + lane; i < end; i += 64) {
    float e = hs[cs[i]] + hdd;
    e = (e >= 0.f) ? e : 0.2f * e;
    mloc = fmaxf(mloc, e);
  }
  for (int off = 32; off; off >>= 1) mloc = fmaxf(mloc, __shfl_xor(mloc, off));
  float m = mloc;
  // denom
  float zloc = 0.f;
  for (int i = beg + lane; i < end; i += 64) {
    float e = hs[cs[i]] + hdd;
    e = (e >= 0.f) ? e : 0.2f * e;
    zloc += expf(e - m);
  }
  for (int off = 32; off; off >>= 1) zloc += __shfl_xor(zloc, off);
  float z = zloc + expf(eself - m);
  float inv_z = 1.f / z;
  // weighted aggregation (all lanes: 2 channels each)
  const float2* H2 = (const float2*)H;
  float2 acc = make_float2(0.f, 0.f);
  for (int i = beg; i < end; ++i) {
    int s = cs[i];
    float e = hs[s] + hdd;
    e = (e >= 0.f) ? e : 0.2f * e;
    float w = expf(e - m) * inv_z;
    float2 hv = H2[(size_t)s * 64 + lane];
    acc.x = fmaf(w, hv.x, acc.x);
    acc.y = fmaf(w, hv.y, acc.y);
  }
  {
    float w = expf(eself - m) * inv_z;
    float2 hv = H2[(size_t)d * 64 + lane];
    acc.x = fmaf(w, hv.x, acc.x);
    acc.y = fmaf(w, hv.y, acc.y);
  }
  float2 b2 = ((const float2*)bias)[lane];
  acc.x = fmaxf(acc.x + b2.x, 0.f);
  acc.y = fmaxf(acc.y + b2.y, 0.f);
  // topk gate
  float2 p2 = ((const float2*)poolP)[lane];
  float dot = acc.x * p2.x + acc.y * p2.y;
  for (int off = 32; off; off >>= 1) dot += __shfl_xor(dot, off);
  float sc = tanhf(dot / pn[0]);
  acc.x *= sc;
  acc.y *= sc;
  ((float2*)Xout)[(size_t)d * 64 + lane] = acc;
}

__global__ void group_bounds(const int* __restrict__ batch, int* __restrict__ gs, int* __restrict__ ge, int n) {
  int i = blockIdx.x * 256 + threadIdx.x;
  if (i >= n) return;
  int b = batch[i];
  if (i == 0 || batch[i - 1] != b) gs[b] = i;
  if (i == n - 1 || batch[i + 1] != b) ge[b] = i + 1;
}

// per-group max & mean, accumulated into x123 (block = group, 128 threads = channels)
__global__ __launch_bounds__(128) void pool_kernel(const float* __restrict__ X, const int* __restrict__ gs,
                                                   const int* __restrict__ ge, float* __restrict__ x123) {
  int g = blockIdx.x;
  int c = threadIdx.x;
  int beg = gs[g], end = ge[g];
  int cnt = end - beg;
  if (cnt <= 0) return;
  float mx = -FLT_MAX, sm = 0.f;
  for (int i = beg; i < end; ++i) {
    float v = X[(size_t)i * D + c];
    mx = fmaxf(mx, v);
    sm += v;
  }
  x123[(size_t)g * 256 + c] += mx;
  x123[(size_t)g * 256 + 128 + c] += sm / (float)cnt;
}

// xDP = relu(x123 @ lin1_W + lin1_b)  (block = row)
__global__ __launch_bounds__(128) void lin1_kernel(const float* __restrict__ x123, const float* __restrict__ W,
                                                   const float* __restrict__ b, float* __restrict__ xb) {
  __shared__ float row[256];
  int g = blockIdx.x;
  int c = threadIdx.x;
  row[c] = x123[(size_t)g * 256 + c];
  row[c + 128] = x123[(size_t)g * 256 + 128 + c];
  __syncthreads();
  float acc = b[c];
#pragma unroll 8
  for (int k = 0; k < 256; ++k) acc = fmaf(row[k], W[k * 128 + c], acc);
  xb[(size_t)g * D + c] = fmaxf(acc, 0.f);
}

__global__ void xse_kernel(const float* __restrict__ emb, const int* __restrict__ x_ids,
                           const int* __restrict__ nDrugPtr, int nProtein, float* __restrict__ xb) {
  int idx = blockIdx.x * 256 + threadIdx.x;  // (N_BIG-G_GROUPS)*64 float2 units
  int r = idx >> 6, lane = idx & 63;
  int off = nDrugPtr[0] + nProtein;
  int id = x_ids[off + r];
  ((float2*)xb)[(size_t)(G_GROUPS + r) * 64 + lane] = ((const float2*)(emb + (size_t)id * D))[lane];
}

__global__ void dis_kernel(const int* __restrict__ deg, float* __restrict__ dis, int n) {
  int i = blockIdx.x * 256 + threadIdx.x;
  if (i < n) dis[i] = 1.f / sqrtf((float)(deg[i] + 1));
}

// GCN aggregation: out[d] = relu( sum_in dis[s]*dis[d]*y[s] + dis[d]^2*y[d] + b )
__global__ __launch_bounds__(256) void gcn_aggr(const float* __restrict__ Y, const float* __restrict__ dis,
                                                const int* __restrict__ rp, const int* __restrict__ cs,
                                                const float* __restrict__ b, float* __restrict__ Xout, int N) {
  int gid = blockIdx.x * blockDim.x + threadIdx.x;
  int d = gid >> 6;
  int lane = threadIdx.x & 63;
  if (d >= N) return;
  float dd = dis[d];
  const float2* Y2 = (const float2*)Y;
  float2 acc = make_float2(0.f, 0.f);
  int beg = rp[d], end = rp[d + 1];
  for (int i = beg; i < end; ++i) {
    int s = cs[i];
    float w = dis[s] * dd;
    float2 yv = Y2[(size_t)s * 64 + lane];
    acc.x = fmaf(w, yv.x, acc.x);
    acc.y = fmaf(w, yv.y, acc.y);
  }
  {
    float w = dd * dd;
    float2 yv = Y2[(size_t)d * 64 + lane];
    acc.x = fmaf(w, yv.x, acc.x);
    acc.y = fmaf(w, yv.y, acc.y);
  }
  float2 b2 = ((const float2*)b)[lane];
  float2 o;
  o.x = fmaxf(acc.x + b2.x, 0.f);
  o.y = fmaxf(acc.y + b2.y, 0.f);
  ((float2*)Xout)[(size_t)d * 64 + lane] = o;
}

__global__ void gather_emb(const float* __restrict__ emb, const int* __restrict__ ids, float* __restrict__ out,
                           int n) {
  int idx = blockIdx.x * 256 + threadIdx.x;  // n*64 float2 units
  int node = idx >> 6, lane = idx & 63;
  if (node >= n) return;
  ((float2*)out)[(size_t)idx] = ((const float2*)(emb + (size_t)ids[node] * D))[lane];
}

__global__ void out_gather(const float* __restrict__ xb, const int* __restrict__ dn, const int* __restrict__ sn,
                           float* __restrict__ out) {
  int idx = blockIdx.x * 256 + threadIdx.x;  // 13000*64 float2 units
  int r = idx >> 6, lane = idx & 63;
  int s = (r < 1000) ? dn[r] : (r < 6000) ? sn[r - 1000] : (r - 6000);
  ((float2*)out)[(size_t)idx] = ((const float2*)(xb + (size_t)s * D))[lane];
}

extern "C" void kernel_launch(void* const* d_in, const int* in_sizes, int n_in, void* d_out, int out_size,
                              void* d_ws, size_t ws_size, hipStream_t stream) {
  const int* x_ids = (const int*)d_in[0];
  const int* drugE = (const int*)d_in[1];
  const int* drugNodes = (const int*)d_in[3];
  const int* seNodes = (const int*)d_in[4];
  int nProtein = in_sizes[5];
  const int* atom_x = (const int*)d_in[7];
  const int* atomE = (const int*)d_in[8];
  const int* atom_batch = (const int*)d_in[9];
  const int* nDrugPtr = (const int*)d_in[10];
  const float* emb = (const float*)d_in[11];
  const float* gatW[3] = {(const float*)d_in[12], (const float*)d_in[17], (const float*)d_in[22]};
  const float* attS[3] = {(const float*)d_in[13], (const float*)d_in[18], (const float*)d_in[23]};
  const float* attD[3] = {(const float*)d_in[14], (const float*)d_in[19], (const float*)d_in[24]};
  const float* gatB[3] = {(const float*)d_in[15], (const float*)d_in[20], (const float*)d_in[25]};
  const float* poolP[3] = {(const float*)d_in[16], (const float*)d_in[21], (const float*)d_in[26]};
  const float* lin1_W = (const float*)d_in[27];
  const float* lin1_b = (const float*)d_in[28];
  const float* gcn1_W = (const float*)d_in[29];
  const float* gcn1_b = (const float*)d_in[30];
  const float* gcn2_W = (const float*)d_in[31];
  const float* gcn2_b = (const float*)d_in[32];
  float* out = (float*)d_out;
  (void)n_in; (void)out_size; (void)ws_size;

  char* ws = (char*)d_ws;
  size_t off = 0;
  auto alloc = [&](size_t bytes) -> char* {
    char* p = ws + off;
    off += (bytes + 255) & ~(size_t)255;
    return p;
  };
  float* bufA = (float*)alloc((size_t)N_ATOMS * D * 4);
  float* bufB = (float*)alloc((size_t)N_ATOMS * D * 4);
  float* hs = (float*)alloc((size_t)N_ATOMS * 4);
  float* hd = (float*)alloc((size_t)N_ATOMS * 4);
  float* x123 = (float*)alloc((size_t)G_GROUPS * 256 * 4);
  float* xb1 = (float*)alloc((size_t)N_BIG * D * 4);
  float* xb2 = (float*)alloc((size_t)N_BIG * D * 4);
  int* rpA = (int*)alloc((size_t)(N_ATOMS + 1) * 4);
  int* csA = (int*)alloc((size_t)E_ATOMS * 4);
  int* degA = (int*)alloc((size_t)N_ATOMS * 4);
  int* rpB = (int*)alloc((size_t)(N_BIG + 1) * 4);
  int* csB = (int*)alloc((size_t)E_BIG * 4);
  int* degB = (int*)alloc((size_t)N_BIG * 4);
  float* disB = (float*)alloc((size_t)N_BIG * 4);
  int* gs = (int*)alloc((size_t)G_GROUPS * 4);
  int* ge = (int*)alloc((size_t)G_GROUPS * 4);
  int* bsums = (int*)alloc(256 * 4);
  float* pn = (float*)alloc(256);

  const int* asrc = atomE;
  const int* adst = atomE + E_ATOMS;
  const int* dsrc = drugE;
  const int* ddst = drugE + E_BIG;

  // ---- atom CSR ----
  hipMemsetAsync(degA, 0, (size_t)N_ATOMS * 4, stream);
  count_kernel<<<ceil_div(E_ATOMS, 256), 256, 0, stream>>>(adst, degA, E_ATOMS);
  scan_phase1<<<ceil_div(N_ATOMS, 1024), 256, 0, stream>>>(degA, rpA, bsums, N_ATOMS);
  scan_phase2<<<1, 256, 0, stream>>>(bsums, rpA + N_ATOMS, ceil_div(N_ATOMS, 1024));
  scan_phase3<<<ceil_div(N_ATOMS, 256), 256, 0, stream>>>(rpA, bsums, N_ATOMS);
  hipMemsetAsync(degA, 0, (size_t)N_ATOMS * 4, stream);
  fill_kernel<<<ceil_div(E_ATOMS, 256), 256, 0, stream>>>(asrc, adst, rpA, degA, csA, E_ATOMS);

  // ---- big CSR + dis ----
  hipMemsetAsync(degB, 0, (size_t)N_BIG * 4, stream);
  count_kernel<<<ceil_div(E_BIG, 256), 256, 0, stream>>>(ddst, degB, E_BIG);
  scan_phase1<<<ceil_div(N_BIG, 1024), 256, 0, stream>>>(degB, rpB, bsums, N_BIG);
  scan_phase2<<<1, 256, 0, stream>>>(bsums, rpB + N_BIG, ceil_div(N_BIG, 1024));
  scan_phase3<<<ceil_div(N_BIG, 256), 256, 0, stream>>>(rpB, bsums, N_BIG);
  dis_kernel<<<ceil_div(N_BIG, 256), 256, 0, stream>>>(degB, disB, N_BIG);
  hipMemsetAsync(degB, 0, (size_t)N_BIG * 4, stream);
  fill_kernel<<<ceil_div(E_BIG, 256), 256, 0, stream>>>(dsrc, ddst, rpB, degB, csB, E_BIG);

  // ---- group ranges ----
  hipMemsetAsync(gs, 0, (size_t)G_GROUPS * 4, stream);
  hipMemsetAsync(ge, 0, (size_t)G_GROUPS * 4, stream);
  group_bounds<<<ceil_div(N_ATOMS, 256), 256, 0, stream>>>(atom_batch, gs, ge, N_ATOMS);

  // ---- atom features ----
  gather_emb<<<N_ATOMS * 64 / 256, 256, 0, stream>>>(emb, atom_x, bufA, N_ATOMS);
  hipMemsetAsync(x123, 0, (size_t)G_GROUPS * 256 * 4, stream);

  // ---- 3 GAT layers ----
  for (int L = 0; L < 3; ++L) {
    gemm_k128<<<ceil_div(N_ATOMS, 64), 256, 0, stream>>>(bufA, gatW[L], bufB, N_ATOMS);
    row_dots<<<N_ATOMS * 64 / 256, 256, 0, stream>>>(bufB, attS[L], attD[L], hs, hd, N_ATOMS);
    pnorm_kernel<<<1, 64, 0, stream>>>(poolP[L], pn);
    gat_aggr<<<N_ATOMS * 64 / 256, 256, 0, stream>>>(bufB, hs, hd, rpA, csA, gatB[L], poolP[L], pn, bufA, N_ATOMS);
    pool_kernel<<<G_GROUPS, 128, 0, stream>>>(bufA, gs, ge, x123);
  }

  // ---- MLP + big-graph node features ----
  lin1_kernel<<<G_GROUPS, 128, 0, stream>>>(x123, lin1_W, lin1_b, xb1);
  xse_kernel<<<(N_BIG - G_GROUPS) * 64 / 256, 256, 0, stream>>>(emb, x_ids, nDrugPtr, nProtein, xb1);

  // ---- 2 GCN layers ----
  gemm_k128<<<ceil_div(N_BIG, 64), 256, 0, stream>>>(xb1, gcn1_W, bufB, N_BIG);
  gcn_aggr<<<N_BIG * 64 / 256, 256, 0, stream>>>(bufB, disB, rpB, csB, gcn1_b, xb2, N_BIG);
  gemm_k128<<<ceil_div(N_BIG, 64), 256, 0, stream>>>(xb2, gcn2_W, bufB, N_BIG);
  gcn_aggr<<<N_BIG * 64 / 256, 256, 0, stream>>>(bufB, disB, rpB, csB, gcn2_b, xb1, N_BIG);

  // ---- outputs ----
  out_gather<<<13000 * 64 / 256, 256, 0, stream>>>(xb1, drugNodes, seNodes, out);
}

// Round 2
// 1072.485 us; speedup vs baseline: 1.7882x; 1.7882x over previous
//
#include <hip/hip_runtime.h>
#include <cfloat>
#include <cmath>

#define D 128
#define N_ATOMS 200000
#define E_ATOMS 800000
#define G_GROUPS 2000
#define N_BIG 7000
#define E_BIG 200000

static inline int ceil_div(int a, int b) { return (a + b - 1) / b; }

typedef __attribute__((ext_vector_type(8))) short bf16x8;
typedef __attribute__((ext_vector_type(4))) float f32x4;

__device__ inline short f2bf(float f) {
  unsigned u = __builtin_bit_cast(unsigned, f);
  u = (u + 0x7FFF + ((u >> 16) & 1)) >> 16;
  return (short)u;
}
__device__ inline float bf2f(short h) {
  unsigned u = ((unsigned)(unsigned short)h) << 16;
  return __builtin_bit_cast(float, u);
}

// ---------------- CSR build ----------------
__global__ void count_kernel(const int* __restrict__ dst, int* __restrict__ deg, int E) {
  int i = blockIdx.x * 256 + threadIdx.x;
  if (i < E) atomicAdd(&deg[dst[i]], 1);
}

__global__ void fill_kernel(const int* __restrict__ src, const int* __restrict__ dst,
                            const int* __restrict__ rp, int* __restrict__ fill,
                            int* __restrict__ cs, int E) {
  int i = blockIdx.x * 256 + threadIdx.x;
  if (i < E) {
    int d = dst[i];
    int pos = rp[d] + atomicAdd(&fill[d], 1);
    cs[pos] = src[i];
  }
}

// 3-phase exclusive scan (1024 elements per block in phase 1)
__global__ __launch_bounds__(256) void scan_phase1(const int* __restrict__ in, int* __restrict__ out,
                                                   int* __restrict__ bsums, int n) {
  __shared__ int lds[256];
  int t = threadIdx.x;
  int base = blockIdx.x * 1024;
  int v[4];
  int s = 0;
#pragma unroll
  for (int j = 0; j < 4; ++j) {
    int i = base + t * 4 + j;
    v[j] = (i < n) ? in[i] : 0;
    s += v[j];
  }
  lds[t] = s;
  __syncthreads();
  for (int off = 1; off < 256; off <<= 1) {
    int x = (t >= off) ? lds[t - off] : 0;
    __syncthreads();
    lds[t] += x;
    __syncthreads();
  }
  int excl = lds[t] - s;
  if (t == 255) bsums[blockIdx.x] = lds[255];
  int run = excl;
#pragma unroll
  for (int j = 0; j < 4; ++j) {
    int i = base + t * 4 + j;
    if (i < n) out[i] = run;
    run += v[j];
  }
}

__global__ __launch_bounds__(256) void scan_phase2(int* __restrict__ bsums, int* __restrict__ total_out, int nb) {
  __shared__ int lds[256];
  int t = threadIdx.x;
  int s = (t < nb) ? bsums[t] : 0;
  lds[t] = s;
  __syncthreads();
  for (int off = 1; off < 256; off <<= 1) {
    int x = (t >= off) ? lds[t - off] : 0;
    __syncthreads();
    lds[t] += x;
    __syncthreads();
  }
  if (t < nb) bsums[t] = lds[t] - s;
  if (t == 255) total_out[0] = lds[255];
}

__global__ void scan_phase3(int* __restrict__ out, const int* __restrict__ bsums, int n) {
  int i = blockIdx.x * 256 + threadIdx.x;
  if (i < n) out[i] += bsums[i >> 10];
}

// ---------------- MFMA GEMM: H[M,128] = X[M,128] @ W[128,128] (split-bf16, ~fp32 acc) ----
// Optionally fuses hs = H@aS, hd = H@aD (GAT attention dots).
__global__ __launch_bounds__(256) void gemm_mfma(const float* __restrict__ X, const float* __restrict__ W,
                                                 float* __restrict__ H, float* __restrict__ hs,
                                                 float* __restrict__ hd, const float* __restrict__ aS,
                                                 const float* __restrict__ aD, int M) {
  __shared__ short WhT[128 * 128];  // transposed [col][k], XOR-swizzled
  __shared__ short WlT[128 * 128];
  int t = threadIdx.x;
  {
    int col = t & 127;
    int half = t >> 7;
#pragma unroll
    for (int kg = 0; kg < 8; ++kg) {
      int k0 = kg * 16 + half * 8;
      short vh[8], vl[8];
#pragma unroll
      for (int j = 0; j < 8; ++j) {
        float w = W[(k0 + j) * 128 + col];
        short hh = f2bf(w);
        vh[j] = hh;
        vl[j] = f2bf(w - bf2f(hh));
      }
      int byte_off = (col * 256 + k0 * 2) ^ ((col & 7) << 4);
      *(bf16x8*)((char*)WhT + byte_off) = *(bf16x8*)vh;
      *(bf16x8*)((char*)WlT + byte_off) = *(bf16x8*)vl;
    }
  }
  __syncthreads();
  int wave = t >> 6, lane = t & 63;
  int lr = lane & 15, lq = lane >> 4;
  int row0 = blockIdx.x * 128 + wave * 32;
  f32x4 acc[2][8];
#pragma unroll
  for (int rt = 0; rt < 2; ++rt)
#pragma unroll
    for (int ct = 0; ct < 8; ++ct) acc[rt][ct] = (f32x4){0.f, 0.f, 0.f, 0.f};

#pragma unroll
  for (int ks = 0; ks < 4; ++ks) {
    int k8 = ks * 32 + lq * 8;
    bf16x8 Ah[2], Al[2];
#pragma unroll
    for (int rt = 0; rt < 2; ++rt) {
      int row = row0 + rt * 16 + lr;
      float f[8];
      if (row < M) {
        float4 v0 = *(const float4*)(X + (size_t)row * D + k8);
        float4 v1 = *(const float4*)(X + (size_t)row * D + k8 + 4);
        f[0] = v0.x; f[1] = v0.y; f[2] = v0.z; f[3] = v0.w;
        f[4] = v1.x; f[5] = v1.y; f[6] = v1.z; f[7] = v1.w;
      } else {
#pragma unroll
        for (int j = 0; j < 8; ++j) f[j] = 0.f;
      }
      short ah[8], al[8];
#pragma unroll
      for (int j = 0; j < 8; ++j) {
        ah[j] = f2bf(f[j]);
        al[j] = f2bf(f[j] - bf2f(ah[j]));
      }
      Ah[rt] = *(bf16x8*)ah;
      Al[rt] = *(bf16x8*)al;
    }
#pragma unroll
    for (int ct = 0; ct < 8; ++ct) {
      int col = ct * 16 + lr;
      int byte_off = (col * 256 + k8 * 2) ^ ((col & 7) << 4);
      bf16x8 Bh = *(bf16x8*)((char*)WhT + byte_off);
      bf16x8 Bl = *(bf16x8*)((char*)WlT + byte_off);
#pragma unroll
      for (int rt = 0; rt < 2; ++rt) {
        acc[rt][ct] = __builtin_amdgcn_mfma_f32_16x16x32_bf16(Ah[rt], Bh, acc[rt][ct], 0, 0, 0);
        acc[rt][ct] = __builtin_amdgcn_mfma_f32_16x16x32_bf16(Al[rt], Bh, acc[rt][ct], 0, 0, 0);
        acc[rt][ct] = __builtin_amdgcn_mfma_f32_16x16x32_bf16(Ah[rt], Bl, acc[rt][ct], 0, 0, 0);
      }
    }
  }
  // C/D layout (measured): col = lane&15, row = (lane>>4)*4 + i
#pragma unroll
  for (int rt = 0; rt < 2; ++rt)
#pragma unroll
    for (int ct = 0; ct < 8; ++ct) {
      int col = ct * 16 + lr;
#pragma unroll
      for (int i = 0; i < 4; ++i) {
        int row = row0 + rt * 16 + lq * 4 + i;
        if (row < M) H[(size_t)row * D + col] = acc[rt][ct][i];
      }
    }
  if (aS) {
    float sA[8], sD[8];
#pragma unroll
    for (int ct = 0; ct < 8; ++ct) {
      sA[ct] = aS[ct * 16 + lr];
      sD[ct] = aD[ct * 16 + lr];
    }
#pragma unroll
    for (int rt = 0; rt < 2; ++rt)
#pragma unroll
      for (int i = 0; i < 4; ++i) {
        float ps = 0.f, pd = 0.f;
#pragma unroll
        for (int ct = 0; ct < 8; ++ct) {
          ps = fmaf(acc[rt][ct][i], sA[ct], ps);
          pd = fmaf(acc[rt][ct][i], sD[ct], pd);
        }
#pragma unroll
        for (int off = 1; off < 16; off <<= 1) {
          ps += __shfl_xor(ps, off);
          pd += __shfl_xor(pd, off);
        }
        int row = row0 + rt * 16 + lq * 4 + i;
        if (lr == 0 && row < M) {
          hs[row] = ps;
          hd[row] = pd;
        }
      }
  }
}

__global__ void pnorm_kernel(const float* __restrict__ p, float* __restrict__ pn) {
  int t = threadIdx.x;  // 64
  float2 v = ((const float2*)p)[t];
  float s = v.x * v.x + v.y * v.y;
  for (int off = 32; off; off >>= 1) s += __shfl_xor(s, off);
  if (t == 0) pn[0] = sqrtf(s);
}

// per-destination GAT softmax + weighted aggregation + bias + relu + topk gate (one wave per dst)
__global__ __launch_bounds__(256) void gat_aggr(const float* __restrict__ H, const float* __restrict__ hs,
                                                const float* __restrict__ hd, const int* __restrict__ rp,
                                                const int* __restrict__ cs, const float* __restrict__ bias,
                                                const float* __restrict__ poolP, const float* __restrict__ pn,
                                                float* __restrict__ Xout, int N) {
  int gid = blockIdx.x * blockDim.x + threadIdx.x;
  int d = gid >> 6;
  int lane = threadIdx.x & 63;
  if (d >= N) return;
  int beg = rp[d], end = rp[d + 1];
  float hdd = hd[d];
  float eself = hs[d] + hdd;
  eself = (eself >= 0.f) ? eself : 0.2f * eself;
  float mloc = eself;
  for (int i = beg + lane; i < end; i += 64) {
    float e = hs[cs[i]] + hdd;
    e = (e >= 0.f) ? e : 0.2f * e;
    mloc = fmaxf(mloc, e);
  }
  for (int off = 32; off; off >>= 1) mloc = fmaxf(mloc, __shfl_xor(mloc, off));
  float m = mloc;
  float zloc = 0.f;
  for (int i = beg + lane; i < end; i += 64) {
    float e = hs[cs[i]] + hdd;
    e = (e >= 0.f) ? e : 0.2f * e;
    zloc += expf(e - m);
  }
  for (int off = 32; off; off >>= 1) zloc += __shfl_xor(zloc, off);
  float z = zloc + expf(eself - m);
  float inv_z = 1.f / z;
  const float2* H2 = (const float2*)H;
  float2 acc = make_float2(0.f, 0.f);
  for (int i = beg; i < end; ++i) {
    int s = cs[i];
    float e = hs[s] + hdd;
    e = (e >= 0.f) ? e : 0.2f * e;
    float w = expf(e - m) * inv_z;
    float2 hv = H2[(size_t)s * 64 + lane];
    acc.x = fmaf(w, hv.x, acc.x);
    acc.y = fmaf(w, hv.y, acc.y);
  }
  {
    float w = expf(eself - m) * inv_z;
    float2 hv = H2[(size_t)d * 64 + lane];
    acc.x = fmaf(w, hv.x, acc.x);
    acc.y = fmaf(w, hv.y, acc.y);
  }
  float2 b2 = ((const float2*)bias)[lane];
  acc.x = fmaxf(acc.x + b2.x, 0.f);
  acc.y = fmaxf(acc.y + b2.y, 0.f);
  float2 p2 = ((const float2*)poolP)[lane];
  float dot = acc.x * p2.x + acc.y * p2.y;
  for (int off = 32; off; off >>= 1) dot += __shfl_xor(dot, off);
  float sc = tanhf(dot / pn[0]);
  acc.x *= sc;
  acc.y *= sc;
  ((float2*)Xout)[(size_t)d * 64 + lane] = acc;
}

__global__ void group_bounds(const int* __restrict__ batch, int* __restrict__ gs, int* __restrict__ ge, int n) {
  int i = blockIdx.x * 256 + threadIdx.x;
  if (i >= n) return;
  int b = batch[i];
  if (i == 0 || batch[i - 1] != b) gs[b] = i;
  if (i == n - 1 || batch[i + 1] != b) ge[b] = i + 1;
}

// per-group max & mean, accumulated into x123 (block = group, 128 threads = channels)
__global__ __launch_bounds__(128) void pool_kernel(const float* __restrict__ X, const int* __restrict__ gs,
                                                   const int* __restrict__ ge, float* __restrict__ x123) {
  int g = blockIdx.x;
  int c = threadIdx.x;
  int beg = gs[g], end = ge[g];
  int cnt = end - beg;
  if (cnt <= 0) return;
  float mx = -FLT_MAX, sm = 0.f;
  for (int i = beg; i < end; ++i) {
    float v = X[(size_t)i * D + c];
    mx = fmaxf(mx, v);
    sm += v;
  }
  x123[(size_t)g * 256 + c] += mx;
  x123[(size_t)g * 256 + 128 + c] += sm / (float)cnt;
}

// xDP = relu(x123 @ lin1_W + lin1_b)  (block = row)
__global__ __launch_bounds__(128) void lin1_kernel(const float* __restrict__ x123, const float* __restrict__ W,
                                                   const float* __restrict__ b, float* __restrict__ xb) {
  __shared__ float row[256];
  int g = blockIdx.x;
  int c = threadIdx.x;
  row[c] = x123[(size_t)g * 256 + c];
  row[c + 128] = x123[(size_t)g * 256 + 128 + c];
  __syncthreads();
  float acc = b[c];
#pragma unroll 8
  for (int k = 0; k < 256; ++k) acc = fmaf(row[k], W[k * 128 + c], acc);
  xb[(size_t)g * D + c] = fmaxf(acc, 0.f);
}

__global__ void xse_kernel(const float* __restrict__ emb, const int* __restrict__ x_ids,
                           const int* __restrict__ nDrugPtr, int nProtein, float* __restrict__ xb) {
  int idx = blockIdx.x * 256 + threadIdx.x;
  int r = idx >> 6, lane = idx & 63;
  int off = nDrugPtr[0] + nProtein;
  int id = x_ids[off + r];
  ((float2*)xb)[(size_t)(G_GROUPS + r) * 64 + lane] = ((const float2*)(emb + (size_t)id * D))[lane];
}

__global__ void dis_kernel(const int* __restrict__ deg, float* __restrict__ dis, int n) {
  int i = blockIdx.x * 256 + threadIdx.x;
  if (i < n) dis[i] = 1.f / sqrtf((float)(deg[i] + 1));
}

// GCN aggregation: out[d] = relu( sum_in dis[s]*dis[d]*y[s] + dis[d]^2*y[d] + b )
__global__ __launch_bounds__(256) void gcn_aggr(const float* __restrict__ Y, const float* __restrict__ dis,
                                                const int* __restrict__ rp, const int* __restrict__ cs,
                                                const float* __restrict__ b, float* __restrict__ Xout, int N) {
  int gid = blockIdx.x * blockDim.x + threadIdx.x;
  int d = gid >> 6;
  int lane = threadIdx.x & 63;
  if (d >= N) return;
  float dd = dis[d];
  const float2* Y2 = (const float2*)Y;
  float2 acc = make_float2(0.f, 0.f);
  int beg = rp[d], end = rp[d + 1];
  for (int i = beg; i < end; ++i) {
    int s = cs[i];
    float w = dis[s] * dd;
    float2 yv = Y2[(size_t)s * 64 + lane];
    acc.x = fmaf(w, yv.x, acc.x);
    acc.y = fmaf(w, yv.y, acc.y);
  }
  {
    float w = dd * dd;
    float2 yv = Y2[(size_t)d * 64 + lane];
    acc.x = fmaf(w, yv.x, acc.x);
    acc.y = fmaf(w, yv.y, acc.y);
  }
  float2 b2 = ((const float2*)b)[lane];
  float2 o;
  o.x = fmaxf(acc.x + b2.x, 0.f);
  o.y = fmaxf(acc.y + b2.y, 0.f);
  ((float2*)Xout)[(size_t)d * 64 + lane] = o;
}

__global__ void gather_emb(const float* __restrict__ emb, const int* __restrict__ ids, float* __restrict__ out,
                           int n) {
  int idx = blockIdx.x * 256 + threadIdx.x;
  int node = idx >> 6, lane = idx & 63;
  if (node >= n) return;
  ((float2*)out)[(size_t)idx] = ((const float2*)(emb + (size_t)ids[node] * D))[lane];
}

__global__ void out_gather(const float* __restrict__ xb, const int* __restrict__ dn, const int* __restrict__ sn,
                           float* __restrict__ out) {
  int idx = blockIdx.x * 256 + threadIdx.x;
  int r = idx >> 6, lane = idx & 63;
  int s = (r < 1000) ? dn[r] : (r < 6000) ? sn[r - 1000] : (r - 6000);
  ((float2*)out)[(size_t)idx] = ((const float2*)(xb + (size_t)s * D))[lane];
}

extern "C" void kernel_launch(void* const* d_in, const int* in_sizes, int n_in, void* d_out, int out_size,
                              void* d_ws, size_t ws_size, hipStream_t stream) {
  const int* x_ids = (const int*)d_in[0];
  const int* drugE = (const int*)d_in[1];
  const int* drugNodes = (const int*)d_in[3];
  const int* seNodes = (const int*)d_in[4];
  int nProtein = in_sizes[5];
  const int* atom_x = (const int*)d_in[7];
  const int* atomE = (const int*)d_in[8];
  const int* atom_batch = (const int*)d_in[9];
  const int* nDrugPtr = (const int*)d_in[10];
  const float* emb = (const float*)d_in[11];
  const float* gatW[3] = {(const float*)d_in[12], (const float*)d_in[17], (const float*)d_in[22]};
  const float* attS[3] = {(const float*)d_in[13], (const float*)d_in[18], (const float*)d_in[23]};
  const float* attD[3] = {(const float*)d_in[14], (const float*)d_in[19], (const float*)d_in[24]};
  const float* gatB[3] = {(const float*)d_in[15], (const float*)d_in[20], (const float*)d_in[25]};
  const float* poolP[3] = {(const float*)d_in[16], (const float*)d_in[21], (const float*)d_in[26]};
  const float* lin1_W = (const float*)d_in[27];
  const float* lin1_b = (const float*)d_in[28];
  const float* gcn1_W = (const float*)d_in[29];
  const float* gcn1_b = (const float*)d_in[30];
  const float* gcn2_W = (const float*)d_in[31];
  const float* gcn2_b = (const float*)d_in[32];
  float* out = (float*)d_out;
  (void)n_in; (void)out_size; (void)ws_size;

  char* ws = (char*)d_ws;
  size_t off = 0;
  auto alloc = [&](size_t bytes) -> char* {
    char* p = ws + off;
    off += (bytes + 255) & ~(size_t)255;
    return p;
  };
  float* bufA = (float*)alloc((size_t)N_ATOMS * D * 4);
  float* bufB = (float*)alloc((size_t)N_ATOMS * D * 4);
  float* hs = (float*)alloc((size_t)N_ATOMS * 4);
  float* hd = (float*)alloc((size_t)N_ATOMS * 4);
  float* x123 = (float*)alloc((size_t)G_GROUPS * 256 * 4);
  float* xb1 = (float*)alloc((size_t)N_BIG * D * 4);
  float* xb2 = (float*)alloc((size_t)N_BIG * D * 4);
  int* rpA = (int*)alloc((size_t)(N_ATOMS + 1) * 4);
  int* csA = (int*)alloc((size_t)E_ATOMS * 4);
  int* degA = (int*)alloc((size_t)N_ATOMS * 4);
  int* rpB = (int*)alloc((size_t)(N_BIG + 1) * 4);
  int* csB = (int*)alloc((size_t)E_BIG * 4);
  int* degB = (int*)alloc((size_t)N_BIG * 4);
  float* disB = (float*)alloc((size_t)N_BIG * 4);
  int* gs = (int*)alloc((size_t)G_GROUPS * 4);
  int* ge = (int*)alloc((size_t)G_GROUPS * 4);
  int* bsums = (int*)alloc(256 * 4);
  float* pn = (float*)alloc(256);

  const int* asrc = atomE;
  const int* adst = atomE + E_ATOMS;
  const int* dsrc = drugE;
  const int* ddst = drugE + E_BIG;

  // ---- atom CSR ----
  hipMemsetAsync(degA, 0, (size_t)N_ATOMS * 4, stream);
  count_kernel<<<ceil_div(E_ATOMS, 256), 256, 0, stream>>>(adst, degA, E_ATOMS);
  scan_phase1<<<ceil_div(N_ATOMS, 1024), 256, 0, stream>>>(degA, rpA, bsums, N_ATOMS);
  scan_phase2<<<1, 256, 0, stream>>>(bsums, rpA + N_ATOMS, ceil_div(N_ATOMS, 1024));
  scan_phase3<<<ceil_div(N_ATOMS, 256), 256, 0, stream>>>(rpA, bsums, N_ATOMS);
  hipMemsetAsync(degA, 0, (size_t)N_ATOMS * 4, stream);
  fill_kernel<<<ceil_div(E_ATOMS, 256), 256, 0, stream>>>(asrc, adst, rpA, degA, csA, E_ATOMS);

  // ---- big CSR + dis ----
  hipMemsetAsync(degB, 0, (size_t)N_BIG * 4, stream);
  count_kernel<<<ceil_div(E_BIG, 256), 256, 0, stream>>>(ddst, degB, E_BIG);
  scan_phase1<<<ceil_div(N_BIG, 1024), 256, 0, stream>>>(degB, rpB, bsums, N_BIG);
  scan_phase2<<<1, 256, 0, stream>>>(bsums, rpB + N_BIG, ceil_div(N_BIG, 1024));
  scan_phase3<<<ceil_div(N_BIG, 256), 256, 0, stream>>>(rpB, bsums, N_BIG);
  dis_kernel<<<ceil_div(N_BIG, 256), 256, 0, stream>>>(degB, disB, N_BIG);
  hipMemsetAsync(degB, 0, (size_t)N_BIG * 4, stream);
  fill_kernel<<<ceil_div(E_BIG, 256), 256, 0, stream>>>(dsrc, ddst, rpB, degB, csB, E_BIG);

  // ---- group ranges ----
  hipMemsetAsync(gs, 0, (size_t)G_GROUPS * 4, stream);
  hipMemsetAsync(ge, 0, (size_t)G_GROUPS * 4, stream);
  group_bounds<<<ceil_div(N_ATOMS, 256), 256, 0, stream>>>(atom_batch, gs, ge, N_ATOMS);

  // ---- atom features ----
  gather_emb<<<N_ATOMS * 64 / 256, 256, 0, stream>>>(emb, atom_x, bufA, N_ATOMS);
  hipMemsetAsync(x123, 0, (size_t)G_GROUPS * 256 * 4, stream);

  // ---- 3 GAT layers ----
  for (int L = 0; L < 3; ++L) {
    gemm_mfma<<<ceil_div(N_ATOMS, 128), 256, 0, stream>>>(bufA, gatW[L], bufB, hs, hd, attS[L], attD[L],
                                                          N_ATOMS);
    pnorm_kernel<<<1, 64, 0, stream>>>(poolP[L], pn);
    gat_aggr<<<N_ATOMS * 64 / 256, 256, 0, stream>>>(bufB, hs, hd, rpA, csA, gatB[L], poolP[L], pn, bufA, N_ATOMS);
    pool_kernel<<<G_GROUPS, 128, 0, stream>>>(bufA, gs, ge, x123);
  }

  // ---- MLP + big-graph node features ----
  lin1_kernel<<<G_GROUPS, 128, 0, stream>>>(x123, lin1_W, lin1_b, xb1);
  xse_kernel<<<(N_BIG - G_GROUPS) * 64 / 256, 256, 0, stream>>>(emb, x_ids, nDrugPtr, nProtein, xb1);

  // ---- 2 GCN layers ----
  gemm_mfma<<<ceil_div(N_BIG, 128), 256, 0, stream>>>(xb1, gcn1_W, bufB, nullptr, nullptr, nullptr, nullptr,
                                                      N_BIG);
  gcn_aggr<<<N_BIG * 64 / 256, 256, 0, stream>>>(bufB, disB, rpB, csB, gcn1_b, xb2, N_BIG);
  gemm_mfma<<<ceil_div(N_BIG, 128), 256, 0, stream>>>(xb2, gcn2_W, bufB, nullptr, nullptr, nullptr, nullptr,
                                                      N_BIG);
  gcn_aggr<<<N_BIG * 64 / 256, 256, 0, stream>>>(bufB, disB, rpB, csB, gcn2_b, xb1, N_BIG);

  // ---- outputs ----
  out_gather<<<13000 * 64 / 256, 256, 0, stream>>>(xb1, drugNodes, seNodes, out);
}

// Round 3
// 838.506 us; speedup vs baseline: 2.2871x; 1.2790x over previous
//
#include <hip/hip_runtime.h>
#include <cfloat>
#include <cmath>

#define D 128
#define N_ATOMS 200000
#define E_ATOMS 800000
#define G_GROUPS 2000
#define N_BIG 7000
#define E_BIG 200000

static inline int ceil_div(int a, int b) { return (a + b - 1) / b; }

typedef __attribute__((ext_vector_type(8))) short bf16x8;
typedef __attribute__((ext_vector_type(4))) float f32x4;

__device__ inline short f2bf(float f) {
  unsigned u = __builtin_bit_cast(unsigned, f);
  u = (u + 0x7FFF + ((u >> 16) & 1)) >> 16;
  return (short)u;
}
__device__ inline float bf2f(short h) {
  unsigned u = ((unsigned)(unsigned short)h) << 16;
  return __builtin_bit_cast(float, u);
}
__device__ inline float bflo(unsigned p) { return __builtin_bit_cast(float, p << 16); }
__device__ inline float bfhi(unsigned p) { return __builtin_bit_cast(float, p & 0xFFFF0000u); }
__device__ inline unsigned bfpack(float x, float y) {
  return ((unsigned)(unsigned short)f2bf(x)) | (((unsigned)(unsigned short)f2bf(y)) << 16);
}

// ---------------- CSR build ----------------
__global__ void count_kernel(const int* __restrict__ dst, int* __restrict__ deg, int E) {
  int i = blockIdx.x * 256 + threadIdx.x;
  if (i < E) atomicAdd(&deg[dst[i]], 1);
}

__global__ void fill_kernel(const int* __restrict__ src, const int* __restrict__ dst,
                            const int* __restrict__ rp, int* __restrict__ fill,
                            int* __restrict__ cs, int E) {
  int i = blockIdx.x * 256 + threadIdx.x;
  if (i < E) {
    int d = dst[i];
    int pos = rp[d] + atomicAdd(&fill[d], 1);
    cs[pos] = src[i];
  }
}

__global__ __launch_bounds__(256) void scan_phase1(const int* __restrict__ in, int* __restrict__ out,
                                                   int* __restrict__ bsums, int n) {
  __shared__ int lds[256];
  int t = threadIdx.x;
  int base = blockIdx.x * 1024;
  int v[4];
  int s = 0;
#pragma unroll
  for (int j = 0; j < 4; ++j) {
    int i = base + t * 4 + j;
    v[j] = (i < n) ? in[i] : 0;
    s += v[j];
  }
  lds[t] = s;
  __syncthreads();
  for (int off = 1; off < 256; off <<= 1) {
    int x = (t >= off) ? lds[t - off] : 0;
    __syncthreads();
    lds[t] += x;
    __syncthreads();
  }
  int excl = lds[t] - s;
  if (t == 255) bsums[blockIdx.x] = lds[255];
  int run = excl;
#pragma unroll
  for (int j = 0; j < 4; ++j) {
    int i = base + t * 4 + j;
    if (i < n) out[i] = run;
    run += v[j];
  }
}

__global__ __launch_bounds__(256) void scan_phase2(int* __restrict__ bsums, int* __restrict__ total_out, int nb) {
  __shared__ int lds[256];
  int t = threadIdx.x;
  int s = (t < nb) ? bsums[t] : 0;
  lds[t] = s;
  __syncthreads();
  for (int off = 1; off < 256; off <<= 1) {
    int x = (t >= off) ? lds[t - off] : 0;
    __syncthreads();
    lds[t] += x;
    __syncthreads();
  }
  if (t < nb) bsums[t] = lds[t] - s;
  if (t == 255) total_out[0] = lds[255];
}

__global__ void scan_phase3(int* __restrict__ out, const int* __restrict__ bsums, int n) {
  int i = blockIdx.x * 256 + threadIdx.x;
  if (i < n) out[i] += bsums[i >> 10];
}

// ---------------- MFMA GEMM: H[M,128] = A[M,128](bf16) @ W[128,128](fp32, split hi/lo) ----
// Output H in bf16; optionally fuses hs = H@aS, hd = H@aD (fp32, from fp32 acc).
__global__ __launch_bounds__(256) void gemm_bf16(const short* __restrict__ A, const float* __restrict__ W,
                                                 short* __restrict__ H, float* __restrict__ hs,
                                                 float* __restrict__ hd, const float* __restrict__ aS,
                                                 const float* __restrict__ aD, int M) {
  __shared__ short WhT[128 * 128];  // transposed [col][k], XOR-swizzled
  __shared__ short WlT[128 * 128];
  int t = threadIdx.x;
  {
    int col = t & 127;
    int half = t >> 7;
#pragma unroll
    for (int kg = 0; kg < 8; ++kg) {
      int k0 = kg * 16 + half * 8;
      short vh[8], vl[8];
#pragma unroll
      for (int j = 0; j < 8; ++j) {
        float w = W[(k0 + j) * 128 + col];
        short hh = f2bf(w);
        vh[j] = hh;
        vl[j] = f2bf(w - bf2f(hh));
      }
      int byte_off = (col * 256 + k0 * 2) ^ ((col & 7) << 4);
      *(bf16x8*)((char*)WhT + byte_off) = *(bf16x8*)vh;
      *(bf16x8*)((char*)WlT + byte_off) = *(bf16x8*)vl;
    }
  }
  __syncthreads();
  int wave = t >> 6, lane = t & 63;
  int lr = lane & 15, lq = lane >> 4;
  int row0 = blockIdx.x * 128 + wave * 32;
  f32x4 acc[2][8];
#pragma unroll
  for (int rt = 0; rt < 2; ++rt)
#pragma unroll
    for (int ct = 0; ct < 8; ++ct) acc[rt][ct] = (f32x4){0.f, 0.f, 0.f, 0.f};

#pragma unroll
  for (int ks = 0; ks < 4; ++ks) {
    int k8 = ks * 32 + lq * 8;
    bf16x8 Af[2];
#pragma unroll
    for (int rt = 0; rt < 2; ++rt) {
      int row = row0 + rt * 16 + lr;
      if (row < M) {
        Af[rt] = *(const bf16x8*)(A + (size_t)row * D + k8);
      } else {
        Af[rt] = (bf16x8){0, 0, 0, 0, 0, 0, 0, 0};
      }
    }
#pragma unroll
    for (int ct = 0; ct < 8; ++ct) {
      int col = ct * 16 + lr;
      int byte_off = (col * 256 + k8 * 2) ^ ((col & 7) << 4);
      bf16x8 Bh = *(bf16x8*)((char*)WhT + byte_off);
      bf16x8 Bl = *(bf16x8*)((char*)WlT + byte_off);
#pragma unroll
      for (int rt = 0; rt < 2; ++rt) {
        acc[rt][ct] = __builtin_amdgcn_mfma_f32_16x16x32_bf16(Af[rt], Bh, acc[rt][ct], 0, 0, 0);
        acc[rt][ct] = __builtin_amdgcn_mfma_f32_16x16x32_bf16(Af[rt], Bl, acc[rt][ct], 0, 0, 0);
      }
    }
  }
  // C/D layout: col = lane&15, row = (lane>>4)*4 + i
#pragma unroll
  for (int rt = 0; rt < 2; ++rt)
#pragma unroll
    for (int ct = 0; ct < 8; ++ct) {
      int col = ct * 16 + lr;
#pragma unroll
      for (int i = 0; i < 4; ++i) {
        int row = row0 + rt * 16 + lq * 4 + i;
        if (row < M) H[(size_t)row * D + col] = f2bf(acc[rt][ct][i]);
      }
    }
  if (aS) {
    float sA[8], sD[8];
#pragma unroll
    for (int ct = 0; ct < 8; ++ct) {
      sA[ct] = aS[ct * 16 + lr];
      sD[ct] = aD[ct * 16 + lr];
    }
#pragma unroll
    for (int rt = 0; rt < 2; ++rt)
#pragma unroll
      for (int i = 0; i < 4; ++i) {
        float ps = 0.f, pd = 0.f;
#pragma unroll
        for (int ct = 0; ct < 8; ++ct) {
          ps = fmaf(acc[rt][ct][i], sA[ct], ps);
          pd = fmaf(acc[rt][ct][i], sD[ct], pd);
        }
#pragma unroll
        for (int off = 1; off < 16; off <<= 1) {
          ps += __shfl_xor(ps, off);
          pd += __shfl_xor(pd, off);
        }
        int row = row0 + rt * 16 + lq * 4 + i;
        if (lr == 0 && row < M) {
          hs[row] = ps;
          hd[row] = pd;
        }
      }
  }
}

__global__ void pnorm_kernel(const float* __restrict__ p, float* __restrict__ pn) {
  int t = threadIdx.x;  // 64
  float2 v = ((const float2*)p)[t];
  float s = v.x * v.x + v.y * v.y;
  for (int off = 32; off; off >>= 1) s += __shfl_xor(s, off);
  if (t == 0) pn[0] = sqrtf(s);
}

__device__ inline float leaky(float e) { return (e >= 0.f) ? e : 0.2f * e; }

// per-destination GAT softmax + aggregation + bias + relu + topk gate (one wave per dst)
// fast path (deg<=64): each lane owns one edge, exp computed once, (src,w) shfl-broadcast.
__global__ __launch_bounds__(256) void gat_aggr(const short* __restrict__ H, const float* __restrict__ hs,
                                                const float* __restrict__ hd, const int* __restrict__ rp,
                                                const int* __restrict__ cs, const float* __restrict__ bias,
                                                const float* __restrict__ poolP, const float* __restrict__ pn,
                                                short* __restrict__ Xout, int N) {
  int gid = blockIdx.x * blockDim.x + threadIdx.x;
  int d = gid >> 6;
  int lane = threadIdx.x & 63;
  if (d >= N) return;
  int beg = rp[d], end = rp[d + 1];
  int cnt = end - beg;
  float hdd = hd[d];
  float eself = leaky(hs[d] + hdd);
  const unsigned* H2 = (const unsigned*)H;  // bf16 pair per lane
  float2 acc = make_float2(0.f, 0.f);
  float wself_n;
  if (cnt <= 64) {
    int s = (lane < cnt) ? cs[beg + lane] : 0;
    float e = (lane < cnt) ? leaky(hs[s] + hdd) : -FLT_MAX;
    float m = fmaxf(e, eself);
#pragma unroll
    for (int off = 32; off; off >>= 1) m = fmaxf(m, __shfl_xor(m, off));
    float w = (lane < cnt) ? expf(e - m) : 0.f;
    float z = w;
#pragma unroll
    for (int off = 32; off; off >>= 1) z += __shfl_xor(z, off);
    float wself = expf(eself - m);
    z += wself;
    float inv_z = 1.f / z;
    for (int j = 0; j < cnt; ++j) {
      int sj = __shfl(s, j);
      float wj = __shfl(w, j) * inv_z;
      unsigned hv = H2[(size_t)sj * 64 + lane];
      acc.x = fmaf(wj, bflo(hv), acc.x);
      acc.y = fmaf(wj, bfhi(hv), acc.y);
    }
    wself_n = wself * inv_z;
  } else {
    float mloc = eself;
    for (int i = beg + lane; i < end; i += 64) mloc = fmaxf(mloc, leaky(hs[cs[i]] + hdd));
#pragma unroll
    for (int off = 32; off; off >>= 1) mloc = fmaxf(mloc, __shfl_xor(mloc, off));
    float m = mloc;
    float zloc = 0.f;
    for (int i = beg + lane; i < end; i += 64) zloc += expf(leaky(hs[cs[i]] + hdd) - m);
#pragma unroll
    for (int off = 32; off; off >>= 1) zloc += __shfl_xor(zloc, off);
    float wself = expf(eself - m);
    float inv_z = 1.f / (zloc + wself);
    for (int i = beg; i < end; ++i) {
      int s = cs[i];
      float w = expf(leaky(hs[s] + hdd) - m) * inv_z;
      unsigned hv = H2[(size_t)s * 64 + lane];
      acc.x = fmaf(w, bflo(hv), acc.x);
      acc.y = fmaf(w, bfhi(hv), acc.y);
    }
    wself_n = wself * inv_z;
  }
  {
    unsigned hv = H2[(size_t)d * 64 + lane];
    acc.x = fmaf(wself_n, bflo(hv), acc.x);
    acc.y = fmaf(wself_n, bfhi(hv), acc.y);
  }
  float2 b2 = ((const float2*)bias)[lane];
  acc.x = fmaxf(acc.x + b2.x, 0.f);
  acc.y = fmaxf(acc.y + b2.y, 0.f);
  float2 p2 = ((const float2*)poolP)[lane];
  float dot = acc.x * p2.x + acc.y * p2.y;
#pragma unroll
  for (int off = 32; off; off >>= 1) dot += __shfl_xor(dot, off);
  float sc = tanhf(dot / pn[0]);
  acc.x *= sc;
  acc.y *= sc;
  ((unsigned*)Xout)[(size_t)d * 64 + lane] = bfpack(acc.x, acc.y);
}

__global__ void group_bounds(const int* __restrict__ batch, int* __restrict__ gs, int* __restrict__ ge, int n) {
  int i = blockIdx.x * 256 + threadIdx.x;
  if (i >= n) return;
  int b = batch[i];
  if (i == 0 || batch[i - 1] != b) gs[b] = i;
  if (i == n - 1 || batch[i + 1] != b) ge[b] = i + 1;
}

// per-group max & mean (bf16 in, fp32 x123 accumulate)
__global__ __launch_bounds__(128) void pool_kernel(const short* __restrict__ X, const int* __restrict__ gs,
                                                   const int* __restrict__ ge, float* __restrict__ x123) {
  int g = blockIdx.x;
  int c = threadIdx.x;
  int beg = gs[g], end = ge[g];
  int cnt = end - beg;
  if (cnt <= 0) return;
  float mx = -FLT_MAX, sm = 0.f;
  for (int i = beg; i < end; ++i) {
    float v = bf2f(X[(size_t)i * D + c]);
    mx = fmaxf(mx, v);
    sm += v;
  }
  x123[(size_t)g * 256 + c] += mx;
  x123[(size_t)g * 256 + 128 + c] += sm / (float)cnt;
}

// xDP = relu(x123 @ lin1_W + lin1_b), bf16 out
__global__ __launch_bounds__(128) void lin1_kernel(const float* __restrict__ x123, const float* __restrict__ W,
                                                   const float* __restrict__ b, short* __restrict__ xb) {
  __shared__ float row[256];
  int g = blockIdx.x;
  int c = threadIdx.x;
  row[c] = x123[(size_t)g * 256 + c];
  row[c + 128] = x123[(size_t)g * 256 + 128 + c];
  __syncthreads();
  float acc = b[c];
#pragma unroll 8
  for (int k = 0; k < 256; ++k) acc = fmaf(row[k], W[k * 128 + c], acc);
  xb[(size_t)g * D + c] = f2bf(fmaxf(acc, 0.f));
}

__global__ void xse_kernel(const float* __restrict__ emb, const int* __restrict__ x_ids,
                           const int* __restrict__ nDrugPtr, int nProtein, short* __restrict__ xb) {
  int idx = blockIdx.x * 256 + threadIdx.x;
  int r = idx >> 6, lane = idx & 63;
  int off = nDrugPtr[0] + nProtein;
  int id = x_ids[off + r];
  float2 v = ((const float2*)(emb + (size_t)id * D))[lane];
  ((unsigned*)xb)[(size_t)(G_GROUPS + r) * 64 + lane] = bfpack(v.x, v.y);
}

__global__ void dis_kernel(const int* __restrict__ deg, float* __restrict__ dis, int n) {
  int i = blockIdx.x * 256 + threadIdx.x;
  if (i < n) dis[i] = 1.f / sqrtf((float)(deg[i] + 1));
}

// GCN aggregation, bf16 in; writes bf16 (outB) or fp32 (outF)
__global__ __launch_bounds__(256) void gcn_aggr(const short* __restrict__ Y, const float* __restrict__ dis,
                                                const int* __restrict__ rp, const int* __restrict__ cs,
                                                const float* __restrict__ b, short* __restrict__ outB,
                                                float* __restrict__ outF, int N) {
  int gid = blockIdx.x * blockDim.x + threadIdx.x;
  int d = gid >> 6;
  int lane = threadIdx.x & 63;
  if (d >= N) return;
  float dd = dis[d];
  const unsigned* Y2 = (const unsigned*)Y;
  float2 acc = make_float2(0.f, 0.f);
  int beg = rp[d], end = rp[d + 1];
  for (int i = beg; i < end; ++i) {
    int s = cs[i];
    float w = dis[s] * dd;
    unsigned yv = Y2[(size_t)s * 64 + lane];
    acc.x = fmaf(w, bflo(yv), acc.x);
    acc.y = fmaf(w, bfhi(yv), acc.y);
  }
  {
    float w = dd * dd;
    unsigned yv = Y2[(size_t)d * 64 + lane];
    acc.x = fmaf(w, bflo(yv), acc.x);
    acc.y = fmaf(w, bfhi(yv), acc.y);
  }
  float2 b2 = ((const float2*)b)[lane];
  float2 o;
  o.x = fmaxf(acc.x + b2.x, 0.f);
  o.y = fmaxf(acc.y + b2.y, 0.f);
  if (outF)
    ((float2*)outF)[(size_t)d * 64 + lane] = o;
  else
    ((unsigned*)outB)[(size_t)d * 64 + lane] = bfpack(o.x, o.y);
}

__global__ void gather_emb(const float* __restrict__ emb, const int* __restrict__ ids, short* __restrict__ out,
                           int n) {
  int idx = blockIdx.x * 256 + threadIdx.x;
  int node = idx >> 6, lane = idx & 63;
  if (node >= n) return;
  float2 v = ((const float2*)(emb + (size_t)ids[node] * D))[lane];
  ((unsigned*)out)[(size_t)idx] = bfpack(v.x, v.y);
}

__global__ void out_gather(const float* __restrict__ xb, const int* __restrict__ dn, const int* __restrict__ sn,
                           float* __restrict__ out) {
  int idx = blockIdx.x * 256 + threadIdx.x;
  int r = idx >> 6, lane = idx & 63;
  int s = (r < 1000) ? dn[r] : (r < 6000) ? sn[r - 1000] : (r - 6000);
  ((float2*)out)[(size_t)idx] = ((const float2*)(xb + (size_t)s * D))[lane];
}

extern "C" void kernel_launch(void* const* d_in, const int* in_sizes, int n_in, void* d_out, int out_size,
                              void* d_ws, size_t ws_size, hipStream_t stream) {
  const int* x_ids = (const int*)d_in[0];
  const int* drugE = (const int*)d_in[1];
  const int* drugNodes = (const int*)d_in[3];
  const int* seNodes = (const int*)d_in[4];
  int nProtein = in_sizes[5];
  const int* atom_x = (const int*)d_in[7];
  const int* atomE = (const int*)d_in[8];
  const int* atom_batch = (const int*)d_in[9];
  const int* nDrugPtr = (const int*)d_in[10];
  const float* emb = (const float*)d_in[11];
  const float* gatW[3] = {(const float*)d_in[12], (const float*)d_in[17], (const float*)d_in[22]};
  const float* attS[3] = {(const float*)d_in[13], (const float*)d_in[18], (const float*)d_in[23]};
  const float* attD[3] = {(const float*)d_in[14], (const float*)d_in[19], (const float*)d_in[24]};
  const float* gatB[3] = {(const float*)d_in[15], (const float*)d_in[20], (const float*)d_in[25]};
  const float* poolP[3] = {(const float*)d_in[16], (const float*)d_in[21], (const float*)d_in[26]};
  const float* lin1_W = (const float*)d_in[27];
  const float* lin1_b = (const float*)d_in[28];
  const float* gcn1_W = (const float*)d_in[29];
  const float* gcn1_b = (const float*)d_in[30];
  const float* gcn2_W = (const float*)d_in[31];
  const float* gcn2_b = (const float*)d_in[32];
  float* out = (float*)d_out;
  (void)n_in; (void)out_size; (void)ws_size;

  char* ws = (char*)d_ws;
  size_t off = 0;
  auto alloc = [&](size_t bytes) -> char* {
    char* p = ws + off;
    off += (bytes + 255) & ~(size_t)255;
    return p;
  };
  short* bufA = (short*)alloc((size_t)N_ATOMS * D * 2);   // xa (bf16)
  short* bufB = (short*)alloc((size_t)N_ATOMS * D * 2);   // h  (bf16)
  float* hs = (float*)alloc((size_t)N_ATOMS * 4);
  float* hd = (float*)alloc((size_t)N_ATOMS * 4);
  float* x123 = (float*)alloc((size_t)G_GROUPS * 256 * 4);
  short* xb1 = (short*)alloc((size_t)N_BIG * D * 2);
  short* xb2 = (short*)alloc((size_t)N_BIG * D * 2);
  float* xbF = (float*)alloc((size_t)N_BIG * D * 4);
  int* rpA = (int*)alloc((size_t)(N_ATOMS + 1) * 4);
  int* csA = (int*)alloc((size_t)E_ATOMS * 4);
  int* degA = (int*)alloc((size_t)N_ATOMS * 4);
  int* rpB = (int*)alloc((size_t)(N_BIG + 1) * 4);
  int* csB = (int*)alloc((size_t)E_BIG * 4);
  int* degB = (int*)alloc((size_t)N_BIG * 4);
  float* disB = (float*)alloc((size_t)N_BIG * 4);
  int* gs = (int*)alloc((size_t)G_GROUPS * 4);
  int* ge = (int*)alloc((size_t)G_GROUPS * 4);
  int* bsums = (int*)alloc(256 * 4);
  float* pn = (float*)alloc(256);

  const int* asrc = atomE;
  const int* adst = atomE + E_ATOMS;
  const int* dsrc = drugE;
  const int* ddst = drugE + E_BIG;

  // ---- atom CSR ----
  hipMemsetAsync(degA, 0, (size_t)N_ATOMS * 4, stream);
  count_kernel<<<ceil_div(E_ATOMS, 256), 256, 0, stream>>>(adst, degA, E_ATOMS);
  scan_phase1<<<ceil_div(N_ATOMS, 1024), 256, 0, stream>>>(degA, rpA, bsums, N_ATOMS);
  scan_phase2<<<1, 256, 0, stream>>>(bsums, rpA + N_ATOMS, ceil_div(N_ATOMS, 1024));
  scan_phase3<<<ceil_div(N_ATOMS, 256), 256, 0, stream>>>(rpA, bsums, N_ATOMS);
  hipMemsetAsync(degA, 0, (size_t)N_ATOMS * 4, stream);
  fill_kernel<<<ceil_div(E_ATOMS, 256), 256, 0, stream>>>(asrc, adst, rpA, degA, csA, E_ATOMS);

  // ---- big CSR + dis ----
  hipMemsetAsync(degB, 0, (size_t)N_BIG * 4, stream);
  count_kernel<<<ceil_div(E_BIG, 256), 256, 0, stream>>>(ddst, degB, E_BIG);
  scan_phase1<<<ceil_div(N_BIG, 1024), 256, 0, stream>>>(degB, rpB, bsums, N_BIG);
  scan_phase2<<<1, 256, 0, stream>>>(bsums, rpB + N_BIG, ceil_div(N_BIG, 1024));
  scan_phase3<<<ceil_div(N_BIG, 256), 256, 0, stream>>>(rpB, bsums, N_BIG);
  dis_kernel<<<ceil_div(N_BIG, 256), 256, 0, stream>>>(degB, disB, N_BIG);
  hipMemsetAsync(degB, 0, (size_t)N_BIG * 4, stream);
  fill_kernel<<<ceil_div(E_BIG, 256), 256, 0, stream>>>(dsrc, ddst, rpB, degB, csB, E_BIG);

  // ---- group ranges ----
  hipMemsetAsync(gs, 0, (size_t)G_GROUPS * 4, stream);
  hipMemsetAsync(ge, 0, (size_t)G_GROUPS * 4, stream);
  group_bounds<<<ceil_div(N_ATOMS, 256), 256, 0, stream>>>(atom_batch, gs, ge, N_ATOMS);

  // ---- atom features ----
  gather_emb<<<N_ATOMS * 64 / 256, 256, 0, stream>>>(emb, atom_x, bufA, N_ATOMS);
  hipMemsetAsync(x123, 0, (size_t)G_GROUPS * 256 * 4, stream);

  // ---- 3 GAT layers ----
  for (int L = 0; L < 3; ++L) {
    gemm_bf16<<<ceil_div(N_ATOMS, 128), 256, 0, stream>>>(bufA, gatW[L], bufB, hs, hd, attS[L], attD[L],
                                                          N_ATOMS);
    pnorm_kernel<<<1, 64, 0, stream>>>(poolP[L], pn);
    gat_aggr<<<N_ATOMS * 64 / 256, 256, 0, stream>>>(bufB, hs, hd, rpA, csA, gatB[L], poolP[L], pn, bufA,
                                                     N_ATOMS);
    pool_kernel<<<G_GROUPS, 128, 0, stream>>>(bufA, gs, ge, x123);
  }

  // ---- MLP + big-graph node features ----
  lin1_kernel<<<G_GROUPS, 128, 0, stream>>>(x123, lin1_W, lin1_b, xb1);
  xse_kernel<<<(N_BIG - G_GROUPS) * 64 / 256, 256, 0, stream>>>(emb, x_ids, nDrugPtr, nProtein, xb1);

  // ---- 2 GCN layers ----
  gemm_bf16<<<ceil_div(N_BIG, 128), 256, 0, stream>>>(xb1, gcn1_W, bufB, nullptr, nullptr, nullptr, nullptr,
                                                      N_BIG);
  gcn_aggr<<<N_BIG * 64 / 256, 256, 0, stream>>>(bufB, disB, rpB, csB, gcn1_b, xb2, nullptr, N_BIG);
  gemm_bf16<<<ceil_div(N_BIG, 128), 256, 0, stream>>>(xb2, gcn2_W, bufB, nullptr, nullptr, nullptr, nullptr,
                                                      N_BIG);
  gcn_aggr<<<N_BIG * 64 / 256, 256, 0, stream>>>(bufB, disB, rpB, csB, gcn2_b, nullptr, xbF, N_BIG);

  // ---- outputs ----
  out_gather<<<13000 * 64 / 256, 256, 0, stream>>>(xbF, drugNodes, seNodes, out);
}

// Round 4
// 786.011 us; speedup vs baseline: 2.4399x; 1.0668x over previous
//
#include <hip/hip_runtime.h>
#include <cfloat>
#include <cmath>

#define D 128
#define N_ATOMS 200000
#define E_ATOMS 800000
#define G_GROUPS 2000
#define N_BIG 7000
#define E_BIG 200000

static inline int ceil_div(int a, int b) { return (a + b - 1) / b; }

typedef __attribute__((ext_vector_type(8))) short bf16x8;
typedef __attribute__((ext_vector_type(4))) float f32x4;

__device__ inline short f2bf(float f) {
  unsigned u = __builtin_bit_cast(unsigned, f);
  u = (u + 0x7FFF + ((u >> 16) & 1)) >> 16;
  return (short)u;
}
__device__ inline float bf2f(short h) {
  unsigned u = ((unsigned)(unsigned short)h) << 16;
  return __builtin_bit_cast(float, u);
}
__device__ inline float bflo(unsigned p) { return __builtin_bit_cast(float, p << 16); }
__device__ inline float bfhi(unsigned p) { return __builtin_bit_cast(float, p & 0xFFFF0000u); }
__device__ inline unsigned bfpack(float x, float y) {
  return ((unsigned)(unsigned short)f2bf(x)) | (((unsigned)(unsigned short)f2bf(y)) << 16);
}

// ---------------- CSR build ----------------
__global__ void count_kernel(const int* __restrict__ dst, int* __restrict__ deg, int E) {
  int i = blockIdx.x * 256 + threadIdx.x;
  if (i < E) atomicAdd(&deg[dst[i]], 1);
}

__global__ void fill_kernel(const int* __restrict__ src, const int* __restrict__ dst,
                            const int* __restrict__ rp, int* __restrict__ fill,
                            int* __restrict__ cs, int E) {
  int i = blockIdx.x * 256 + threadIdx.x;
  if (i < E) {
    int d = dst[i];
    int pos = rp[d] + atomicAdd(&fill[d], 1);
    cs[pos] = src[i];
  }
}

__global__ __launch_bounds__(256) void scan_phase1(const int* __restrict__ in, int* __restrict__ out,
                                                   int* __restrict__ bsums, int n) {
  __shared__ int lds[256];
  int t = threadIdx.x;
  int base = blockIdx.x * 1024;
  int v[4];
  int s = 0;
#pragma unroll
  for (int j = 0; j < 4; ++j) {
    int i = base + t * 4 + j;
    v[j] = (i < n) ? in[i] : 0;
    s += v[j];
  }
  lds[t] = s;
  __syncthreads();
  for (int off = 1; off < 256; off <<= 1) {
    int x = (t >= off) ? lds[t - off] : 0;
    __syncthreads();
    lds[t] += x;
    __syncthreads();
  }
  int excl = lds[t] - s;
  if (t == 255) bsums[blockIdx.x] = lds[255];
  int run = excl;
#pragma unroll
  for (int j = 0; j < 4; ++j) {
    int i = base + t * 4 + j;
    if (i < n) out[i] = run;
    run += v[j];
  }
}

__global__ __launch_bounds__(256) void scan_phase2(int* __restrict__ bsums, int* __restrict__ total_out, int nb) {
  __shared__ int lds[256];
  int t = threadIdx.x;
  int s = (t < nb) ? bsums[t] : 0;
  lds[t] = s;
  __syncthreads();
  for (int off = 1; off < 256; off <<= 1) {
    int x = (t >= off) ? lds[t - off] : 0;
    __syncthreads();
    lds[t] += x;
    __syncthreads();
  }
  if (t < nb) bsums[t] = lds[t] - s;
  if (t == 255) total_out[0] = lds[255];
}

__global__ void scan_phase3(int* __restrict__ out, const int* __restrict__ bsums, int n) {
  int i = blockIdx.x * 256 + threadIdx.x;
  if (i < n) out[i] += bsums[i >> 10];
}

// ---------------- MFMA GEMM: H[M,128] = A[M,128](bf16) @ W[128,128](fp32, split hi/lo) ----
__global__ __launch_bounds__(256) void gemm_bf16(const short* __restrict__ A, const float* __restrict__ W,
                                                 short* __restrict__ H, float* __restrict__ hs,
                                                 float* __restrict__ hd, const float* __restrict__ aS,
                                                 const float* __restrict__ aD, int M) {
  __shared__ short WhT[128 * 128];  // transposed [col][k], XOR-swizzled
  __shared__ short WlT[128 * 128];
  int t = threadIdx.x;
  {
    int col = t & 127;
    int half = t >> 7;
#pragma unroll
    for (int kg = 0; kg < 8; ++kg) {
      int k0 = kg * 16 + half * 8;
      short vh[8], vl[8];
#pragma unroll
      for (int j = 0; j < 8; ++j) {
        float w = W[(k0 + j) * 128 + col];
        short hh = f2bf(w);
        vh[j] = hh;
        vl[j] = f2bf(w - bf2f(hh));
      }
      int byte_off = (col * 256 + k0 * 2) ^ ((col & 7) << 4);
      *(bf16x8*)((char*)WhT + byte_off) = *(bf16x8*)vh;
      *(bf16x8*)((char*)WlT + byte_off) = *(bf16x8*)vl;
    }
  }
  __syncthreads();
  int wave = t >> 6, lane = t & 63;
  int lr = lane & 15, lq = lane >> 4;
  int row0 = blockIdx.x * 128 + wave * 32;
  f32x4 acc[2][8];
#pragma unroll
  for (int rt = 0; rt < 2; ++rt)
#pragma unroll
    for (int ct = 0; ct < 8; ++ct) acc[rt][ct] = (f32x4){0.f, 0.f, 0.f, 0.f};

#pragma unroll
  for (int ks = 0; ks < 4; ++ks) {
    int k8 = ks * 32 + lq * 8;
    bf16x8 Af[2];
#pragma unroll
    for (int rt = 0; rt < 2; ++rt) {
      int row = row0 + rt * 16 + lr;
      if (row < M) {
        Af[rt] = *(const bf16x8*)(A + (size_t)row * D + k8);
      } else {
        Af[rt] = (bf16x8){0, 0, 0, 0, 0, 0, 0, 0};
      }
    }
#pragma unroll
    for (int ct = 0; ct < 8; ++ct) {
      int col = ct * 16 + lr;
      int byte_off = (col * 256 + k8 * 2) ^ ((col & 7) << 4);
      bf16x8 Bh = *(bf16x8*)((char*)WhT + byte_off);
      bf16x8 Bl = *(bf16x8*)((char*)WlT + byte_off);
#pragma unroll
      for (int rt = 0; rt < 2; ++rt) {
        acc[rt][ct] = __builtin_amdgcn_mfma_f32_16x16x32_bf16(Af[rt], Bh, acc[rt][ct], 0, 0, 0);
        acc[rt][ct] = __builtin_amdgcn_mfma_f32_16x16x32_bf16(Af[rt], Bl, acc[rt][ct], 0, 0, 0);
      }
    }
  }
  // C/D layout: col = lane&15, row = (lane>>4)*4 + i
#pragma unroll
  for (int rt = 0; rt < 2; ++rt)
#pragma unroll
    for (int ct = 0; ct < 8; ++ct) {
      int col = ct * 16 + lr;
#pragma unroll
      for (int i = 0; i < 4; ++i) {
        int row = row0 + rt * 16 + lq * 4 + i;
        if (row < M) H[(size_t)row * D + col] = f2bf(acc[rt][ct][i]);
      }
    }
  if (aS) {
    float sA[8], sD[8];
#pragma unroll
    for (int ct = 0; ct < 8; ++ct) {
      sA[ct] = aS[ct * 16 + lr];
      sD[ct] = aD[ct * 16 + lr];
    }
#pragma unroll
    for (int rt = 0; rt < 2; ++rt)
#pragma unroll
      for (int i = 0; i < 4; ++i) {
        float ps = 0.f, pd = 0.f;
#pragma unroll
        for (int ct = 0; ct < 8; ++ct) {
          ps = fmaf(acc[rt][ct][i], sA[ct], ps);
          pd = fmaf(acc[rt][ct][i], sD[ct], pd);
        }
#pragma unroll
        for (int off = 1; off < 16; off <<= 1) {
          ps += __shfl_xor(ps, off);
          pd += __shfl_xor(pd, off);
        }
        int row = row0 + rt * 16 + lq * 4 + i;
        if (lr == 0 && row < M) {
          hs[row] = ps;
          hd[row] = pd;
        }
      }
  }
}

__global__ void pnorm_kernel(const float* __restrict__ p, float* __restrict__ pn) {
  int t = threadIdx.x;  // 64
  float2 v = ((const float2*)p)[t];
  float s = v.x * v.x + v.y * v.y;
  for (int off = 32; off; off >>= 1) s += __shfl_xor(s, off);
  if (t == 0) pn[0] = sqrtf(s);
}

__device__ inline float leaky(float e) { return (e >= 0.f) ? e : 0.2f * e; }

// per-destination GAT softmax + aggregation + bias + relu + topk gate.
// One wave per dst. Lanes = [4 edge-slots (eg) x 16 channel-chunks (ch)]:
// each iteration gathers 4 edge H-rows in parallel (uint4 = 8 bf16 ch/lane).
__global__ __launch_bounds__(256) void gat_aggr(const short* __restrict__ H, const float* __restrict__ hs,
                                                const float* __restrict__ hd, const int* __restrict__ rp,
                                                const int* __restrict__ cs, const float* __restrict__ bias,
                                                const float* __restrict__ poolP, const float* __restrict__ pn,
                                                short* __restrict__ Xout, int N) {
  int gid = blockIdx.x * blockDim.x + threadIdx.x;
  int d = gid >> 6;
  int lane = threadIdx.x & 63;
  if (d >= N) return;
  int eg = lane >> 4;   // edge slot 0..3
  int ch = lane & 15;   // channel chunk (8 channels)
  int beg = rp[d], end = rp[d + 1];
  int cnt = end - beg;
  float hdd = hd[d];
  float eself = leaky(hs[d] + hdd);
  const uint4* H4 = (const uint4*)H;  // 16 uint4 per row
  float acc[8];
#pragma unroll
  for (int c = 0; c < 8; ++c) acc[c] = 0.f;

  if (cnt < 64) {
    // fast path: lane i owns edge i (i<cnt); lane cnt owns the self-loop.
    int sval = (lane < cnt) ? cs[beg + lane] : d;
    float e = (lane < cnt) ? leaky(hs[sval] + hdd) : -FLT_MAX;
    float m = fmaxf(e, eself);
#pragma unroll
    for (int off = 32; off; off >>= 1) m = fmaxf(m, __shfl_xor(m, off));
    float wv = (lane < cnt) ? expf(e - m) : ((lane == cnt) ? expf(eself - m) : 0.f);
    float z = wv;
#pragma unroll
    for (int off = 32; off; off >>= 1) z += __shfl_xor(z, off);
    float inv_z = 1.f / z;
    int total = cnt + 1;
    for (int it = 0; it * 4 < total; ++it) {
      int j = it * 4 + eg;
      int sj = __shfl(sval, j);
      float wj = __shfl(wv, j) * inv_z;
      if (j < total) {
        uint4 hv = H4[(size_t)sj * 16 + ch];
        acc[0] = fmaf(wj, bflo(hv.x), acc[0]);
        acc[1] = fmaf(wj, bfhi(hv.x), acc[1]);
        acc[2] = fmaf(wj, bflo(hv.y), acc[2]);
        acc[3] = fmaf(wj, bfhi(hv.y), acc[3]);
        acc[4] = fmaf(wj, bflo(hv.z), acc[4]);
        acc[5] = fmaf(wj, bfhi(hv.z), acc[5]);
        acc[6] = fmaf(wj, bflo(hv.w), acc[6]);
        acc[7] = fmaf(wj, bfhi(hv.w), acc[7]);
      }
    }
  } else {
    // generic path (rare): strided softmax, per-iteration weight recompute
    float mloc = eself;
    for (int i = beg + lane; i < end; i += 64) mloc = fmaxf(mloc, leaky(hs[cs[i]] + hdd));
#pragma unroll
    for (int off = 32; off; off >>= 1) mloc = fmaxf(mloc, __shfl_xor(mloc, off));
    float m = mloc;
    float zloc = 0.f;
    for (int i = beg + lane; i < end; i += 64) zloc += expf(leaky(hs[cs[i]] + hdd) - m);
#pragma unroll
    for (int off = 32; off; off >>= 1) zloc += __shfl_xor(zloc, off);
    float z = zloc + expf(eself - m);
    float inv_z = 1.f / z;
    int total = cnt + 1;
    for (int it = 0; it * 4 < total; ++it) {
      int j = it * 4 + eg;
      if (j < total) {
        int sj = (j < cnt) ? cs[beg + j] : d;
        float e = (j < cnt) ? leaky(hs[sj] + hdd) : eself;
        float wj = expf(e - m) * inv_z;
        uint4 hv = H4[(size_t)sj * 16 + ch];
        acc[0] = fmaf(wj, bflo(hv.x), acc[0]);
        acc[1] = fmaf(wj, bfhi(hv.x), acc[1]);
        acc[2] = fmaf(wj, bflo(hv.y), acc[2]);
        acc[3] = fmaf(wj, bfhi(hv.y), acc[3]);
        acc[4] = fmaf(wj, bflo(hv.z), acc[4]);
        acc[5] = fmaf(wj, bfhi(hv.z), acc[5]);
        acc[6] = fmaf(wj, bflo(hv.w), acc[6]);
        acc[7] = fmaf(wj, bfhi(hv.w), acc[7]);
      }
    }
  }
  // reduce across the 4 edge slots
#pragma unroll
  for (int c = 0; c < 8; ++c) {
    acc[c] += __shfl_xor(acc[c], 16);
    acc[c] += __shfl_xor(acc[c], 32);
  }
  // bias + relu
  float4 b0 = ((const float4*)bias)[ch * 2];
  float4 b1 = ((const float4*)bias)[ch * 2 + 1];
  acc[0] = fmaxf(acc[0] + b0.x, 0.f);
  acc[1] = fmaxf(acc[1] + b0.y, 0.f);
  acc[2] = fmaxf(acc[2] + b0.z, 0.f);
  acc[3] = fmaxf(acc[3] + b0.w, 0.f);
  acc[4] = fmaxf(acc[4] + b1.x, 0.f);
  acc[5] = fmaxf(acc[5] + b1.y, 0.f);
  acc[6] = fmaxf(acc[6] + b1.z, 0.f);
  acc[7] = fmaxf(acc[7] + b1.w, 0.f);
  // topk gate
  float4 p0 = ((const float4*)poolP)[ch * 2];
  float4 p1 = ((const float4*)poolP)[ch * 2 + 1];
  float dot = acc[0] * p0.x + acc[1] * p0.y + acc[2] * p0.z + acc[3] * p0.w +
              acc[4] * p1.x + acc[5] * p1.y + acc[6] * p1.z + acc[7] * p1.w;
#pragma unroll
  for (int off = 8; off; off >>= 1) dot += __shfl_xor(dot, off);
  float sc = tanhf(dot / pn[0]);
#pragma unroll
  for (int c = 0; c < 8; ++c) acc[c] *= sc;
  if (eg == 0) {
    uint4 o;
    o.x = bfpack(acc[0], acc[1]);
    o.y = bfpack(acc[2], acc[3]);
    o.z = bfpack(acc[4], acc[5]);
    o.w = bfpack(acc[6], acc[7]);
    ((uint4*)Xout)[(size_t)d * 16 + ch] = o;
  }
}

__global__ void group_bounds(const int* __restrict__ batch, int* __restrict__ gs, int* __restrict__ ge, int n) {
  int i = blockIdx.x * 256 + threadIdx.x;
  if (i >= n) return;
  int b = batch[i];
  if (i == 0 || batch[i - 1] != b) gs[b] = i;
  if (i == n - 1 || batch[i + 1] != b) ge[b] = i + 1;
}

// per-group max & mean (bf16 in, fp32 x123 accumulate); one wave per group, packed loads
__global__ __launch_bounds__(64) void pool_kernel(const short* __restrict__ X, const int* __restrict__ gs,
                                                  const int* __restrict__ ge, float* __restrict__ x123) {
  int g = blockIdx.x;
  int p = threadIdx.x;  // channel pair 0..63
  int beg = gs[g], end = ge[g];
  int cnt = end - beg;
  if (cnt <= 0) return;
  const unsigned* X2 = (const unsigned*)X;
  float mx0 = -FLT_MAX, mx1 = -FLT_MAX, sm0 = 0.f, sm1 = 0.f;
  for (int i = beg; i < end; ++i) {
    unsigned v = X2[(size_t)i * 64 + p];
    float a = bflo(v), b = bfhi(v);
    mx0 = fmaxf(mx0, a);
    mx1 = fmaxf(mx1, b);
    sm0 += a;
    sm1 += b;
  }
  float inv = 1.f / (float)cnt;
  float* xg = x123 + (size_t)g * 256;
  xg[2 * p] += mx0;
  xg[2 * p + 1] += mx1;
  xg[128 + 2 * p] += sm0 * inv;
  xg[128 + 2 * p + 1] += sm1 * inv;
}

// xDP = relu(x123 @ lin1_W + lin1_b), bf16 out
__global__ __launch_bounds__(128) void lin1_kernel(const float* __restrict__ x123, const float* __restrict__ W,
                                                   const float* __restrict__ b, short* __restrict__ xb) {
  __shared__ float row[256];
  int g = blockIdx.x;
  int c = threadIdx.x;
  row[c] = x123[(size_t)g * 256 + c];
  row[c + 128] = x123[(size_t)g * 256 + 128 + c];
  __syncthreads();
  float acc = b[c];
#pragma unroll 8
  for (int k = 0; k < 256; ++k) acc = fmaf(row[k], W[k * 128 + c], acc);
  xb[(size_t)g * D + c] = f2bf(fmaxf(acc, 0.f));
}

__global__ void xse_kernel(const float* __restrict__ emb, const int* __restrict__ x_ids,
                           const int* __restrict__ nDrugPtr, int nProtein, short* __restrict__ xb) {
  int idx = blockIdx.x * 256 + threadIdx.x;
  int r = idx >> 6, lane = idx & 63;
  int off = nDrugPtr[0] + nProtein;
  int id = x_ids[off + r];
  float2 v = ((const float2*)(emb + (size_t)id * D))[lane];
  ((unsigned*)xb)[(size_t)(G_GROUPS + r) * 64 + lane] = bfpack(v.x, v.y);
}

__global__ void dis_kernel(const int* __restrict__ deg, float* __restrict__ dis, int n) {
  int i = blockIdx.x * 256 + threadIdx.x;
  if (i < n) dis[i] = 1.f / sqrtf((float)(deg[i] + 1));
}

// GCN aggregation, bf16 in; writes bf16 (outB) or fp32 (outF)
__global__ __launch_bounds__(256) void gcn_aggr(const short* __restrict__ Y, const float* __restrict__ dis,
                                                const int* __restrict__ rp, const int* __restrict__ cs,
                                                const float* __restrict__ b, short* __restrict__ outB,
                                                float* __restrict__ outF, int N) {
  int gid = blockIdx.x * blockDim.x + threadIdx.x;
  int d = gid >> 6;
  int lane = threadIdx.x & 63;
  if (d >= N) return;
  float dd = dis[d];
  const unsigned* Y2 = (const unsigned*)Y;
  float2 acc = make_float2(0.f, 0.f);
  int beg = rp[d], end = rp[d + 1];
  for (int i = beg; i < end; ++i) {
    int s = cs[i];
    float w = dis[s] * dd;
    unsigned yv = Y2[(size_t)s * 64 + lane];
    acc.x = fmaf(w, bflo(yv), acc.x);
    acc.y = fmaf(w, bfhi(yv), acc.y);
  }
  {
    float w = dd * dd;
    unsigned yv = Y2[(size_t)d * 64 + lane];
    acc.x = fmaf(w, bflo(yv), acc.x);
    acc.y = fmaf(w, bfhi(yv), acc.y);
  }
  float2 b2 = ((const float2*)b)[lane];
  float2 o;
  o.x = fmaxf(acc.x + b2.x, 0.f);
  o.y = fmaxf(acc.y + b2.y, 0.f);
  if (outF)
    ((float2*)outF)[(size_t)d * 64 + lane] = o;
  else
    ((unsigned*)outB)[(size_t)d * 64 + lane] = bfpack(o.x, o.y);
}

// 2 nodes per wave, float4 loads (32 lanes per row)
__global__ void gather_emb(const float* __restrict__ emb, const int* __restrict__ ids, short* __restrict__ out,
                           int n) {
  int idx = blockIdx.x * 256 + threadIdx.x;
  int node = idx >> 5, lane = idx & 31;
  if (node >= n) return;
  float4 v = ((const float4*)(emb + (size_t)ids[node] * D))[lane];
  uint2 o;
  o.x = bfpack(v.x, v.y);
  o.y = bfpack(v.z, v.w);
  ((uint2*)out)[(size_t)node * 32 + lane] = o;
}

__global__ void out_gather(const float* __restrict__ xb, const int* __restrict__ dn, const int* __restrict__ sn,
                           float* __restrict__ out) {
  int idx = blockIdx.x * 256 + threadIdx.x;
  int r = idx >> 6, lane = idx & 63;
  int s = (r < 1000) ? dn[r] : (r < 6000) ? sn[r - 1000] : (r - 6000);
  ((float2*)out)[(size_t)idx] = ((const float2*)(xb + (size_t)s * D))[lane];
}

extern "C" void kernel_launch(void* const* d_in, const int* in_sizes, int n_in, void* d_out, int out_size,
                              void* d_ws, size_t ws_size, hipStream_t stream) {
  const int* x_ids = (const int*)d_in[0];
  const int* drugE = (const int*)d_in[1];
  const int* drugNodes = (const int*)d_in[3];
  const int* seNodes = (const int*)d_in[4];
  int nProtein = in_sizes[5];
  const int* atom_x = (const int*)d_in[7];
  const int* atomE = (const int*)d_in[8];
  const int* atom_batch = (const int*)d_in[9];
  const int* nDrugPtr = (const int*)d_in[10];
  const float* emb = (const float*)d_in[11];
  const float* gatW[3] = {(const float*)d_in[12], (const float*)d_in[17], (const float*)d_in[22]};
  const float* attS[3] = {(const float*)d_in[13], (const float*)d_in[18], (const float*)d_in[23]};
  const float* attD[3] = {(const float*)d_in[14], (const float*)d_in[19], (const float*)d_in[24]};
  const float* gatB[3] = {(const float*)d_in[15], (const float*)d_in[20], (const float*)d_in[25]};
  const float* poolP[3] = {(const float*)d_in[16], (const float*)d_in[21], (const float*)d_in[26]};
  const float* lin1_W = (const float*)d_in[27];
  const float* lin1_b = (const float*)d_in[28];
  const float* gcn1_W = (const float*)d_in[29];
  const float* gcn1_b = (const float*)d_in[30];
  const float* gcn2_W = (const float*)d_in[31];
  const float* gcn2_b = (const float*)d_in[32];
  float* out = (float*)d_out;
  (void)n_in; (void)out_size; (void)ws_size;

  char* ws = (char*)d_ws;
  size_t off = 0;
  auto alloc = [&](size_t bytes) -> char* {
    char* p = ws + off;
    off += (bytes + 255) & ~(size_t)255;
    return p;
  };
  short* bufA = (short*)alloc((size_t)N_ATOMS * D * 2);   // xa (bf16)
  short* bufB = (short*)alloc((size_t)N_ATOMS * D * 2);   // h  (bf16)
  float* hs = (float*)alloc((size_t)N_ATOMS * 4);
  float* hd = (float*)alloc((size_t)N_ATOMS * 4);
  float* x123 = (float*)alloc((size_t)G_GROUPS * 256 * 4);
  short* xb1 = (short*)alloc((size_t)N_BIG * D * 2);
  short* xb2 = (short*)alloc((size_t)N_BIG * D * 2);
  float* xbF = (float*)alloc((size_t)N_BIG * D * 4);
  int* rpA = (int*)alloc((size_t)(N_ATOMS + 1) * 4);
  int* csA = (int*)alloc((size_t)E_ATOMS * 4);
  int* degA = (int*)alloc((size_t)N_ATOMS * 4);
  int* rpB = (int*)alloc((size_t)(N_BIG + 1) * 4);
  int* csB = (int*)alloc((size_t)E_BIG * 4);
  int* degB = (int*)alloc((size_t)N_BIG * 4);
  float* disB = (float*)alloc((size_t)N_BIG * 4);
  int* gs = (int*)alloc((size_t)G_GROUPS * 4);
  int* ge = (int*)alloc((size_t)G_GROUPS * 4);
  int* bsums = (int*)alloc(256 * 4);
  float* pn = (float*)alloc(256);

  const int* asrc = atomE;
  const int* adst = atomE + E_ATOMS;
  const int* dsrc = drugE;
  const int* ddst = drugE + E_BIG;

  // ---- atom CSR ----
  hipMemsetAsync(degA, 0, (size_t)N_ATOMS * 4, stream);
  count_kernel<<<ceil_div(E_ATOMS, 256), 256, 0, stream>>>(adst, degA, E_ATOMS);
  scan_phase1<<<ceil_div(N_ATOMS, 1024), 256, 0, stream>>>(degA, rpA, bsums, N_ATOMS);
  scan_phase2<<<1, 256, 0, stream>>>(bsums, rpA + N_ATOMS, ceil_div(N_ATOMS, 1024));
  scan_phase3<<<ceil_div(N_ATOMS, 256), 256, 0, stream>>>(rpA, bsums, N_ATOMS);
  hipMemsetAsync(degA, 0, (size_t)N_ATOMS * 4, stream);
  fill_kernel<<<ceil_div(E_ATOMS, 256), 256, 0, stream>>>(asrc, adst, rpA, degA, csA, E_ATOMS);

  // ---- big CSR + dis ----
  hipMemsetAsync(degB, 0, (size_t)N_BIG * 4, stream);
  count_kernel<<<ceil_div(E_BIG, 256), 256, 0, stream>>>(ddst, degB, E_BIG);
  scan_phase1<<<ceil_div(N_BIG, 1024), 256, 0, stream>>>(degB, rpB, bsums, N_BIG);
  scan_phase2<<<1, 256, 0, stream>>>(bsums, rpB + N_BIG, ceil_div(N_BIG, 1024));
  scan_phase3<<<ceil_div(N_BIG, 256), 256, 0, stream>>>(rpB, bsums, N_BIG);
  dis_kernel<<<ceil_div(N_BIG, 256), 256, 0, stream>>>(degB, disB, N_BIG);
  hipMemsetAsync(degB, 0, (size_t)N_BIG * 4, stream);
  fill_kernel<<<ceil_div(E_BIG, 256), 256, 0, stream>>>(dsrc, ddst, rpB, degB, csB, E_BIG);

  // ---- group ranges ----
  hipMemsetAsync(gs, 0, (size_t)G_GROUPS * 4, stream);
  hipMemsetAsync(ge, 0, (size_t)G_GROUPS * 4, stream);
  group_bounds<<<ceil_div(N_ATOMS, 256), 256, 0, stream>>>(atom_batch, gs, ge, N_ATOMS);

  // ---- atom features ----
  gather_emb<<<ceil_div(N_ATOMS * 32, 256), 256, 0, stream>>>(emb, atom_x, bufA, N_ATOMS);
  hipMemsetAsync(x123, 0, (size_t)G_GROUPS * 256 * 4, stream);

  // ---- 3 GAT layers ----
  for (int L = 0; L < 3; ++L) {
    gemm_bf16<<<ceil_div(N_ATOMS, 128), 256, 0, stream>>>(bufA, gatW[L], bufB, hs, hd, attS[L], attD[L],
                                                          N_ATOMS);
    pnorm_kernel<<<1, 64, 0, stream>>>(poolP[L], pn);
    gat_aggr<<<N_ATOMS * 64 / 256, 256, 0, stream>>>(bufB, hs, hd, rpA, csA, gatB[L], poolP[L], pn, bufA,
                                                     N_ATOMS);
    pool_kernel<<<G_GROUPS, 64, 0, stream>>>(bufA, gs, ge, x123);
  }

  // ---- MLP + big-graph node features ----
  lin1_kernel<<<G_GROUPS, 128, 0, stream>>>(x123, lin1_W, lin1_b, xb1);
  xse_kernel<<<(N_BIG - G_GROUPS) * 64 / 256, 256, 0, stream>>>(emb, x_ids, nDrugPtr, nProtein, xb1);

  // ---- 2 GCN layers ----
  gemm_bf16<<<ceil_div(N_BIG, 128), 256, 0, stream>>>(xb1, gcn1_W, bufB, nullptr, nullptr, nullptr, nullptr,
                                                      N_BIG);
  gcn_aggr<<<N_BIG * 64 / 256, 256, 0, stream>>>(bufB, disB, rpB, csB, gcn1_b, xb2, nullptr, N_BIG);
  gemm_bf16<<<ceil_div(N_BIG, 128), 256, 0, stream>>>(xb2, gcn2_W, bufB, nullptr, nullptr, nullptr, nullptr,
                                                      N_BIG);
  gcn_aggr<<<N_BIG * 64 / 256, 256, 0, stream>>>(bufB, disB, rpB, csB, gcn2_b, nullptr, xbF, N_BIG);

  // ---- outputs ----
  out_gather<<<13000 * 64 / 256, 256, 0, stream>>>(xbF, drugNodes, seNodes, out);
}

// Round 5
// 614.730 us; speedup vs baseline: 3.1197x; 1.2786x over previous
//
#include <hip/hip_runtime.h>
#include <cfloat>
#include <cmath>

#define D 128
#define N_ATOMS 200000
#define E_ATOMS 800000
#define G_GROUPS 2000
#define N_BIG 7000
#define E_BIG 200000
#define N_ALL (N_ATOMS + N_BIG)
#define E_ALL (E_ATOMS + E_BIG)

static inline int ceil_div(int a, int b) { return (a + b - 1) / b; }

typedef __attribute__((ext_vector_type(8))) short bf16x8;
typedef __attribute__((ext_vector_type(4))) float f32x4;

__device__ inline short f2bf(float f) {
  unsigned u = __builtin_bit_cast(unsigned, f);
  u = (u + 0x7FFF + ((u >> 16) & 1)) >> 16;
  return (short)u;
}
__device__ inline float bf2f(short h) {
  unsigned u = ((unsigned)(unsigned short)h) << 16;
  return __builtin_bit_cast(float, u);
}
__device__ inline float bflo(unsigned p) { return __builtin_bit_cast(float, p << 16); }
__device__ inline float bfhi(unsigned p) { return __builtin_bit_cast(float, p & 0xFFFF0000u); }
__device__ inline unsigned bfpack(float x, float y) {
  return ((unsigned)(unsigned short)f2bf(x)) | (((unsigned)(unsigned short)f2bf(y)) << 16);
}
__device__ inline float leaky(float e) { return fmaxf(e, 0.2f * e); }
__device__ inline float fast_tanh(float x) {
  float cx = fminf(fmaxf(x, -15.f), 15.f);
  float t = __expf(2.f * cx);
  return (t - 1.f) * __frcp_rn(t + 1.f);
}

// ---------------- CSR build (both graphs merged) ----------------
__global__ void count_all(const int* __restrict__ adst, const int* __restrict__ ddst, int* __restrict__ deg) {
  int i = blockIdx.x * 256 + threadIdx.x;
  if (i < E_ATOMS)
    atomicAdd(&deg[adst[i]], 1);
  else if (i < E_ALL)
    atomicAdd(&deg[N_ATOMS + ddst[i - E_ATOMS]], 1);
}

__global__ void fill_all(const int* __restrict__ asrc, const int* __restrict__ adst,
                         const int* __restrict__ dsrc, const int* __restrict__ ddst,
                         const int* __restrict__ rp, int* __restrict__ fill, int* __restrict__ cs) {
  int i = blockIdx.x * 256 + threadIdx.x;
  if (i < E_ATOMS) {
    int idx = adst[i];
    int pos = rp[idx] + atomicAdd(&fill[idx], 1);
    cs[pos] = asrc[i];
  } else if (i < E_ALL) {
    int k = i - E_ATOMS;
    int idx = N_ATOMS + ddst[k];
    int pos = rp[idx] + atomicAdd(&fill[idx], 1);
    cs[pos] = dsrc[k];
  }
}

__global__ __launch_bounds__(256) void scan_phase1(const int* __restrict__ in, int* __restrict__ out,
                                                   int* __restrict__ bsums, int n) {
  __shared__ int lds[256];
  int t = threadIdx.x;
  int base = blockIdx.x * 1024;
  int v[4];
  int s = 0;
#pragma unroll
  for (int j = 0; j < 4; ++j) {
    int i = base + t * 4 + j;
    v[j] = (i < n) ? in[i] : 0;
    s += v[j];
  }
  lds[t] = s;
  __syncthreads();
  for (int off = 1; off < 256; off <<= 1) {
    int x = (t >= off) ? lds[t - off] : 0;
    __syncthreads();
    lds[t] += x;
    __syncthreads();
  }
  int excl = lds[t] - s;
  if (t == 255) bsums[blockIdx.x] = lds[255];
  int run = excl;
#pragma unroll
  for (int j = 0; j < 4; ++j) {
    int i = base + t * 4 + j;
    if (i < n) out[i] = run;
    run += v[j];
  }
}

__global__ __launch_bounds__(256) void scan_phase2(int* __restrict__ bsums, int* __restrict__ total_out, int nb) {
  __shared__ int lds[256];
  int t = threadIdx.x;
  int s = (t < nb) ? bsums[t] : 0;
  lds[t] = s;
  __syncthreads();
  for (int off = 1; off < 256; off <<= 1) {
    int x = (t >= off) ? lds[t - off] : 0;
    __syncthreads();
    lds[t] += x;
    __syncthreads();
  }
  if (t < nb) bsums[t] = lds[t] - s;
  if (t == 255) total_out[0] = lds[255];
}

__global__ void scan_phase3(int* __restrict__ out, const int* __restrict__ bsums, int n) {
  int i = blockIdx.x * 256 + threadIdx.x;
  if (i < n) out[i] += bsums[i >> 10];
}

// ---------------- prep: split 5 W's to swizzled bf16 hi/lo + inv pool-norms ----------------
__global__ __launch_bounds__(256) void prep_kernel(const float* __restrict__ W0, const float* __restrict__ W1,
                                                   const float* __restrict__ W2, const float* __restrict__ W3,
                                                   const float* __restrict__ W4, short* __restrict__ Wsplit,
                                                   const float* __restrict__ p0, const float* __restrict__ p1,
                                                   const float* __restrict__ p2, float* __restrict__ pn) {
  int b = blockIdx.x;
  if (b < 5) {
    const float* W = (b == 0) ? W0 : (b == 1) ? W1 : (b == 2) ? W2 : (b == 3) ? W3 : W4;
    short* dstH = Wsplit + (size_t)b * 32768;
    short* dstL = dstH + 16384;
    int t = threadIdx.x;
    int col = t & 127;
    int half = t >> 7;
#pragma unroll
    for (int kg = 0; kg < 8; ++kg) {
      int k0 = kg * 16 + half * 8;
      short vh[8], vl[8];
#pragma unroll
      for (int j = 0; j < 8; ++j) {
        float w = W[(k0 + j) * 128 + col];
        short hh = f2bf(w);
        vh[j] = hh;
        vl[j] = f2bf(w - bf2f(hh));
      }
      int byte_off = (col * 256 + k0 * 2) ^ ((col & 7) << 4);
      *(bf16x8*)((char*)dstH + byte_off) = *(bf16x8*)vh;
      *(bf16x8*)((char*)dstL + byte_off) = *(bf16x8*)vl;
    }
  } else {
    int t = threadIdx.x;
    int g = t >> 6, lane = t & 63;
    if (g < 3) {
      const float* p = (g == 0) ? p0 : (g == 1) ? p1 : p2;
      float2 v = ((const float2*)p)[lane];
      float s = v.x * v.x + v.y * v.y;
#pragma unroll
      for (int off = 32; off; off >>= 1) s += __shfl_xor(s, off);
      if (lane == 0) pn[g] = 1.f / sqrtf(s);
    }
  }
}

// ---------------- MFMA GEMM: H[M,128] = A[M,128](bf16) @ W (pre-split bf16 hi/lo) ----------
// 512 threads, 8 waves x 32 rows = 256 rows/block. Optionally fuses hs/hd dots.
__global__ __launch_bounds__(512) void gemm_bf16(const short* __restrict__ A, const short* __restrict__ Wsp,
                                                 short* __restrict__ H, float* __restrict__ hs,
                                                 float* __restrict__ hd, const float* __restrict__ aS,
                                                 const float* __restrict__ aD, int M) {
  __shared__ short Wl[2 * 16384];  // hi at 0, lo at +16384 (transposed [col][k], XOR-swizzled)
  int t = threadIdx.x;
  {
    const uint4* src = (const uint4*)Wsp;
    uint4* dst = (uint4*)Wl;
#pragma unroll
    for (int i = 0; i < 8; ++i) dst[t + i * 512] = src[t + i * 512];
  }
  __syncthreads();
  int wave = t >> 6, lane = t & 63;
  int lr = lane & 15, lq = lane >> 4;
  int row0 = blockIdx.x * 256 + wave * 32;
  f32x4 acc[2][8];
#pragma unroll
  for (int rt = 0; rt < 2; ++rt)
#pragma unroll
    for (int ct = 0; ct < 8; ++ct) acc[rt][ct] = (f32x4){0.f, 0.f, 0.f, 0.f};

#pragma unroll
  for (int ks = 0; ks < 4; ++ks) {
    int k8 = ks * 32 + lq * 8;
    bf16x8 Af[2];
#pragma unroll
    for (int rt = 0; rt < 2; ++rt) {
      int row = row0 + rt * 16 + lr;
      if (row < M) {
        Af[rt] = *(const bf16x8*)(A + (size_t)row * D + k8);
      } else {
        Af[rt] = (bf16x8){0, 0, 0, 0, 0, 0, 0, 0};
      }
    }
#pragma unroll
    for (int ct = 0; ct < 8; ++ct) {
      int col = ct * 16 + lr;
      int byte_off = (col * 256 + k8 * 2) ^ ((col & 7) << 4);
      bf16x8 Bh = *(bf16x8*)((char*)Wl + byte_off);
      bf16x8 Bl = *(bf16x8*)((char*)Wl + 32768 + byte_off);
#pragma unroll
      for (int rt = 0; rt < 2; ++rt) {
        acc[rt][ct] = __builtin_amdgcn_mfma_f32_16x16x32_bf16(Af[rt], Bh, acc[rt][ct], 0, 0, 0);
        acc[rt][ct] = __builtin_amdgcn_mfma_f32_16x16x32_bf16(Af[rt], Bl, acc[rt][ct], 0, 0, 0);
      }
    }
  }
  // C/D layout: col = lane&15, row = (lane>>4)*4 + i
#pragma unroll
  for (int rt = 0; rt < 2; ++rt)
#pragma unroll
    for (int ct = 0; ct < 8; ++ct) {
      int col = ct * 16 + lr;
#pragma unroll
      for (int i = 0; i < 4; ++i) {
        int row = row0 + rt * 16 + lq * 4 + i;
        if (row < M) H[(size_t)row * D + col] = f2bf(acc[rt][ct][i]);
      }
    }
  if (aS) {
    float sA[8], sD[8];
#pragma unroll
    for (int ct = 0; ct < 8; ++ct) {
      sA[ct] = aS[ct * 16 + lr];
      sD[ct] = aD[ct * 16 + lr];
    }
#pragma unroll
    for (int rt = 0; rt < 2; ++rt)
#pragma unroll
      for (int i = 0; i < 4; ++i) {
        float ps = 0.f, pd = 0.f;
#pragma unroll
        for (int ct = 0; ct < 8; ++ct) {
          ps = fmaf(acc[rt][ct][i], sA[ct], ps);
          pd = fmaf(acc[rt][ct][i], sD[ct], pd);
        }
#pragma unroll
        for (int off = 1; off < 16; off <<= 1) {
          ps += __shfl_xor(ps, off);
          pd += __shfl_xor(pd, off);
        }
        int row = row0 + rt * 16 + lq * 4 + i;
        if (lr == 0 && row < M) {
          hs[row] = ps;
          hd[row] = pd;
        }
      }
  }
}

// ---------------- GAT edge weights (thread per dst) ----------------
__global__ void edge_weights(const float* __restrict__ hs, const float* __restrict__ hd,
                             const int* __restrict__ rp, const int* __restrict__ cs, float* __restrict__ w,
                             float* __restrict__ wself, float* __restrict__ invz, int N) {
  int d = blockIdx.x * 256 + threadIdx.x;
  if (d >= N) return;
  int beg = rp[d], end = rp[d + 1];
  float hdd = hd[d];
  float es = leaky(hs[d] + hdd);
  float m = es;
  for (int i = beg; i < end; ++i) m = fmaxf(m, leaky(hs[cs[i]] + hdd));
  float z = __expf(es - m);
  wself[d] = z;
  for (int i = beg; i < end; ++i) {
    float ew = __expf(leaky(hs[cs[i]] + hdd) - m);
    w[i] = ew;
    z += ew;
  }
  invz[d] = 1.f / z;
}

// ---------------- GAT gather: out[d] = gate(relu(invz * sum_j w_j H[s_j] + b)) -----------
// One wave per dst, lanes = [4 edge-slots x 16 channel-chunks].
__global__ __launch_bounds__(256) void gat_gather(const short* __restrict__ H, const int* __restrict__ rp,
                                                  const int* __restrict__ cs, const float* __restrict__ w,
                                                  const float* __restrict__ wself,
                                                  const float* __restrict__ invz, const float* __restrict__ bias,
                                                  const float* __restrict__ poolP, const float* __restrict__ pnL,
                                                  short* __restrict__ Xout, int N) {
  int gid = blockIdx.x * blockDim.x + threadIdx.x;
  int d = gid >> 6;
  int lane = threadIdx.x & 63;
  if (d >= N) return;
  int eg = lane >> 4;
  int ch = lane & 15;
  int beg = rp[d], end = rp[d + 1];
  int total = end - beg + 1;
  const uint4* H4 = (const uint4*)H;
  float acc[8];
#pragma unroll
  for (int c = 0; c < 8; ++c) acc[c] = 0.f;
  for (int it = 0; it * 4 < total; ++it) {
    int j = it * 4 + eg;
    if (j < total) {
      int sj;
      float wj;
      if (j < total - 1) {
        sj = cs[beg + j];
        wj = w[beg + j];
      } else {
        sj = d;
        wj = wself[d];
      }
      uint4 hv = H4[(size_t)sj * 16 + ch];
      acc[0] = fmaf(wj, bflo(hv.x), acc[0]);
      acc[1] = fmaf(wj, bfhi(hv.x), acc[1]);
      acc[2] = fmaf(wj, bflo(hv.y), acc[2]);
      acc[3] = fmaf(wj, bfhi(hv.y), acc[3]);
      acc[4] = fmaf(wj, bflo(hv.z), acc[4]);
      acc[5] = fmaf(wj, bfhi(hv.z), acc[5]);
      acc[6] = fmaf(wj, bflo(hv.w), acc[6]);
      acc[7] = fmaf(wj, bfhi(hv.w), acc[7]);
    }
  }
#pragma unroll
  for (int c = 0; c < 8; ++c) {
    acc[c] += __shfl_xor(acc[c], 16);
    acc[c] += __shfl_xor(acc[c], 32);
  }
  float iz = invz[d];
  float4 b0 = ((const float4*)bias)[ch * 2];
  float4 b1 = ((const float4*)bias)[ch * 2 + 1];
  acc[0] = fmaxf(fmaf(acc[0], iz, b0.x), 0.f);
  acc[1] = fmaxf(fmaf(acc[1], iz, b0.y), 0.f);
  acc[2] = fmaxf(fmaf(acc[2], iz, b0.z), 0.f);
  acc[3] = fmaxf(fmaf(acc[3], iz, b0.w), 0.f);
  acc[4] = fmaxf(fmaf(acc[4], iz, b1.x), 0.f);
  acc[5] = fmaxf(fmaf(acc[5], iz, b1.y), 0.f);
  acc[6] = fmaxf(fmaf(acc[6], iz, b1.z), 0.f);
  acc[7] = fmaxf(fmaf(acc[7], iz, b1.w), 0.f);
  float4 p0 = ((const float4*)poolP)[ch * 2];
  float4 p1 = ((const float4*)poolP)[ch * 2 + 1];
  float dot = acc[0] * p0.x + acc[1] * p0.y + acc[2] * p0.z + acc[3] * p0.w + acc[4] * p1.x +
              acc[5] * p1.y + acc[6] * p1.z + acc[7] * p1.w;
#pragma unroll
  for (int off = 8; off; off >>= 1) dot += __shfl_xor(dot, off);
  float sc = fast_tanh(dot * pnL[0]);
#pragma unroll
  for (int c = 0; c < 8; ++c) acc[c] *= sc;
  if (eg == 0) {
    uint4 o;
    o.x = bfpack(acc[0], acc[1]);
    o.y = bfpack(acc[2], acc[3]);
    o.z = bfpack(acc[4], acc[5]);
    o.w = bfpack(acc[6], acc[7]);
    ((uint4*)Xout)[(size_t)d * 16 + ch] = o;
  }
}

__global__ void group_bounds(const int* __restrict__ batch, int* __restrict__ gs, int* __restrict__ ge, int n) {
  int i = blockIdx.x * 256 + threadIdx.x;
  if (i >= n) return;
  int b = batch[i];
  if (i == 0 || batch[i - 1] != b) gs[b] = i;
  if (i == n - 1 || batch[i + 1] != b) ge[b] = i + 1;
}

// per-group max & mean; 4 waves split rows, LDS combine
__global__ __launch_bounds__(256) void pool_kernel(const short* __restrict__ X, const int* __restrict__ gs,
                                                   const int* __restrict__ ge, float* __restrict__ x123) {
  __shared__ float2 mxs[4][64];
  __shared__ float2 sms[4][64];
  int g = blockIdx.x;
  int wv = threadIdx.x >> 6;
  int p = threadIdx.x & 63;
  int beg = gs[g], end = ge[g];
  int cnt = end - beg;
  const unsigned* X2 = (const unsigned*)X;
  float mx0 = -FLT_MAX, mx1 = -FLT_MAX, sm0 = 0.f, sm1 = 0.f;
  for (int i = beg + wv; i < end; i += 4) {
    unsigned v = X2[(size_t)i * 64 + p];
    float a = bflo(v), b = bfhi(v);
    mx0 = fmaxf(mx0, a);
    mx1 = fmaxf(mx1, b);
    sm0 += a;
    sm1 += b;
  }
  mxs[wv][p] = make_float2(mx0, mx1);
  sms[wv][p] = make_float2(sm0, sm1);
  __syncthreads();
  if (threadIdx.x < 64 && cnt > 0) {
#pragma unroll
    for (int k = 1; k < 4; ++k) {
      float2 m2 = mxs[k][p], s2 = sms[k][p];
      mx0 = fmaxf(mx0, m2.x);
      mx1 = fmaxf(mx1, m2.y);
      sm0 += s2.x;
      sm1 += s2.y;
    }
    float inv = 1.f / (float)cnt;
    float* xg = x123 + (size_t)g * 256;
    xg[2 * p] += mx0;
    xg[2 * p + 1] += mx1;
    xg[128 + 2 * p] += sm0 * inv;
    xg[128 + 2 * p + 1] += sm1 * inv;
  }
}

// xDP = relu(x123 @ lin1_W + lin1_b), bf16 out
__global__ __launch_bounds__(128) void lin1_kernel(const float* __restrict__ x123, const float* __restrict__ W,
                                                   const float* __restrict__ b, short* __restrict__ xb) {
  __shared__ float row[256];
  int g = blockIdx.x;
  int c = threadIdx.x;
  row[c] = x123[(size_t)g * 256 + c];
  row[c + 128] = x123[(size_t)g * 256 + 128 + c];
  __syncthreads();
  float acc = b[c];
#pragma unroll 8
  for (int k = 0; k < 256; ++k) acc = fmaf(row[k], W[k * 128 + c], acc);
  xb[(size_t)g * D + c] = f2bf(fmaxf(acc, 0.f));
}

__global__ void xse_kernel(const float* __restrict__ emb, const int* __restrict__ x_ids,
                           const int* __restrict__ nDrugPtr, int nProtein, short* __restrict__ xb) {
  int idx = blockIdx.x * 256 + threadIdx.x;
  int r = idx >> 6, lane = idx & 63;
  int off = nDrugPtr[0] + nProtein;
  int id = x_ids[off + r];
  float2 v = ((const float2*)(emb + (size_t)id * D))[lane];
  ((unsigned*)xb)[(size_t)(G_GROUPS + r) * 64 + lane] = bfpack(v.x, v.y);
}

__global__ void dis_kernel(const int* __restrict__ deg, float* __restrict__ dis, int n) {
  int i = blockIdx.x * 256 + threadIdx.x;
  if (i < n) dis[i] = 1.f / sqrtf((float)(deg[N_ATOMS + i] + 1));
}

// GCN gather: same 4-slot structure; w = dis[s]*dis[d], self dd^2
__global__ __launch_bounds__(256) void gcn_gather(const short* __restrict__ Y, const float* __restrict__ dis,
                                                  const int* __restrict__ rp, const int* __restrict__ cs,
                                                  const float* __restrict__ b, short* __restrict__ outB,
                                                  float* __restrict__ outF, int N) {
  int gid = blockIdx.x * blockDim.x + threadIdx.x;
  int d = gid >> 6;
  int lane = threadIdx.x & 63;
  if (d >= N) return;
  int eg = lane >> 4;
  int ch = lane & 15;
  int beg = rp[d], end = rp[d + 1];
  int total = end - beg + 1;
  float dd = dis[d];
  const uint4* Y4 = (const uint4*)Y;
  float acc[8];
#pragma unroll
  for (int c = 0; c < 8; ++c) acc[c] = 0.f;
  for (int it = 0; it * 4 < total; ++it) {
    int j = it * 4 + eg;
    if (j < total) {
      int sj;
      float wj;
      if (j < total - 1) {
        sj = cs[beg + j];
        wj = dis[sj] * dd;
      } else {
        sj = d;
        wj = dd * dd;
      }
      uint4 hv = Y4[(size_t)sj * 16 + ch];
      acc[0] = fmaf(wj, bflo(hv.x), acc[0]);
      acc[1] = fmaf(wj, bfhi(hv.x), acc[1]);
      acc[2] = fmaf(wj, bflo(hv.y), acc[2]);
      acc[3] = fmaf(wj, bfhi(hv.y), acc[3]);
      acc[4] = fmaf(wj, bflo(hv.z), acc[4]);
      acc[5] = fmaf(wj, bfhi(hv.z), acc[5]);
      acc[6] = fmaf(wj, bflo(hv.w), acc[6]);
      acc[7] = fmaf(wj, bfhi(hv.w), acc[7]);
    }
  }
#pragma unroll
  for (int c = 0; c < 8; ++c) {
    acc[c] += __shfl_xor(acc[c], 16);
    acc[c] += __shfl_xor(acc[c], 32);
  }
  float4 b0 = ((const float4*)b)[ch * 2];
  float4 b1 = ((const float4*)b)[ch * 2 + 1];
  acc[0] = fmaxf(acc[0] + b0.x, 0.f);
  acc[1] = fmaxf(acc[1] + b0.y, 0.f);
  acc[2] = fmaxf(acc[2] + b0.z, 0.f);
  acc[3] = fmaxf(acc[3] + b0.w, 0.f);
  acc[4] = fmaxf(acc[4] + b1.x, 0.f);
  acc[5] = fmaxf(acc[5] + b1.y, 0.f);
  acc[6] = fmaxf(acc[6] + b1.z, 0.f);
  acc[7] = fmaxf(acc[7] + b1.w, 0.f);
  if (eg == 0) {
    if (outF) {
      float4 o0 = make_float4(acc[0], acc[1], acc[2], acc[3]);
      float4 o1 = make_float4(acc[4], acc[5], acc[6], acc[7]);
      ((float4*)outF)[(size_t)d * 32 + ch * 2] = o0;
      ((float4*)outF)[(size_t)d * 32 + ch * 2 + 1] = o1;
    } else {
      uint4 o;
      o.x = bfpack(acc[0], acc[1]);
      o.y = bfpack(acc[2], acc[3]);
      o.z = bfpack(acc[4], acc[5]);
      o.w = bfpack(acc[6], acc[7]);
      ((uint4*)outB)[(size_t)d * 16 + ch] = o;
    }
  }
}

// 2 nodes per wave, float4 loads
__global__ void gather_emb(const float* __restrict__ emb, const int* __restrict__ ids, short* __restrict__ out,
                           int n) {
  int idx = blockIdx.x * 256 + threadIdx.x;
  int node = idx >> 5, lane = idx & 31;
  if (node >= n) return;
  float4 v = ((const float4*)(emb + (size_t)ids[node] * D))[lane];
  uint2 o;
  o.x = bfpack(v.x, v.y);
  o.y = bfpack(v.z, v.w);
  ((uint2*)out)[(size_t)node * 32 + lane] = o;
}

__global__ void out_gather(const float* __restrict__ xb, const int* __restrict__ dn, const int* __restrict__ sn,
                           float* __restrict__ out) {
  int idx = blockIdx.x * 256 + threadIdx.x;
  int r = idx >> 6, lane = idx & 63;
  int s = (r < 1000) ? dn[r] : (r < 6000) ? sn[r - 1000] : (r - 6000);
  ((float2*)out)[(size_t)idx] = ((const float2*)(xb + (size_t)s * D))[lane];
}

extern "C" void kernel_launch(void* const* d_in, const int* in_sizes, int n_in, void* d_out, int out_size,
                              void* d_ws, size_t ws_size, hipStream_t stream) {
  const int* x_ids = (const int*)d_in[0];
  const int* drugE = (const int*)d_in[1];
  const int* drugNodes = (const int*)d_in[3];
  const int* seNodes = (const int*)d_in[4];
  int nProtein = in_sizes[5];
  const int* atom_x = (const int*)d_in[7];
  const int* atomE = (const int*)d_in[8];
  const int* atom_batch = (const int*)d_in[9];
  const int* nDrugPtr = (const int*)d_in[10];
  const float* emb = (const float*)d_in[11];
  const float* gatW[3] = {(const float*)d_in[12], (const float*)d_in[17], (const float*)d_in[22]};
  const float* attS[3] = {(const float*)d_in[13], (const float*)d_in[18], (const float*)d_in[23]};
  const float* attD[3] = {(const float*)d_in[14], (const float*)d_in[19], (const float*)d_in[24]};
  const float* gatB[3] = {(const float*)d_in[15], (const float*)d_in[20], (const float*)d_in[25]};
  const float* poolP[3] = {(const float*)d_in[16], (const float*)d_in[21], (const float*)d_in[26]};
  const float* lin1_W = (const float*)d_in[27];
  const float* lin1_b = (const float*)d_in[28];
  const float* gcn1_W = (const float*)d_in[29];
  const float* gcn1_b = (const float*)d_in[30];
  const float* gcn2_W = (const float*)d_in[31];
  const float* gcn2_b = (const float*)d_in[32];
  float* out = (float*)d_out;
  (void)n_in; (void)out_size; (void)ws_size;

  char* ws = (char*)d_ws;
  size_t off = 0;
  auto alloc = [&](size_t bytes) -> char* {
    char* p = ws + off;
    off += (bytes + 255) & ~(size_t)255;
    return p;
  };
  short* bufA = (short*)alloc((size_t)N_ATOMS * D * 2);  // xa (bf16)
  short* bufB = (short*)alloc((size_t)N_ATOMS * D * 2);  // h  (bf16)
  float* hs = (float*)alloc((size_t)N_ATOMS * 4);
  float* hd = (float*)alloc((size_t)N_ATOMS * 4);
  float* ew = (float*)alloc((size_t)E_ATOMS * 4);
  float* wself = (float*)alloc((size_t)N_ATOMS * 4);
  float* invz = (float*)alloc((size_t)N_ATOMS * 4);
  float* x123 = (float*)alloc((size_t)G_GROUPS * 256 * 4);
  short* xb1 = (short*)alloc((size_t)N_BIG * D * 2);
  short* xb2 = (short*)alloc((size_t)N_BIG * D * 2);
  float* xbF = (float*)alloc((size_t)N_BIG * D * 4);
  short* Wsplit = (short*)alloc((size_t)5 * 32768 * 2);
  int* rp = (int*)alloc((size_t)(N_ALL + 1) * 4);
  int* cs = (int*)alloc((size_t)E_ALL * 4);
  int* deg = (int*)alloc((size_t)N_ALL * 4);
  float* disB = (float*)alloc((size_t)N_BIG * 4);
  int* gs = (int*)alloc((size_t)G_GROUPS * 4);
  int* ge = (int*)alloc((size_t)G_GROUPS * 4);
  int* bsums = (int*)alloc(256 * 4);
  float* pn = (float*)alloc(256);

  const int* asrc = atomE;
  const int* adst = atomE + E_ATOMS;
  const int* dsrc = drugE;
  const int* ddst = drugE + E_BIG;

  // ---- prep (weight split + pool norms) ----
  prep_kernel<<<6, 256, 0, stream>>>(gatW[0], gatW[1], gatW[2], gcn1_W, gcn2_W, Wsplit, poolP[0], poolP[1],
                                     poolP[2], pn);

  // ---- merged CSR ----
  hipMemsetAsync(deg, 0, (size_t)N_ALL * 4, stream);
  count_all<<<ceil_div(E_ALL, 256), 256, 0, stream>>>(adst, ddst, deg);
  scan_phase1<<<ceil_div(N_ALL, 1024), 256, 0, stream>>>(deg, rp, bsums, N_ALL);
  scan_phase2<<<1, 256, 0, stream>>>(bsums, rp + N_ALL, ceil_div(N_ALL, 1024));
  scan_phase3<<<ceil_div(N_ALL, 256), 256, 0, stream>>>(rp, bsums, N_ALL);
  dis_kernel<<<ceil_div(N_BIG, 256), 256, 0, stream>>>(deg, disB, N_BIG);
  hipMemsetAsync(deg, 0, (size_t)N_ALL * 4, stream);
  fill_all<<<ceil_div(E_ALL, 256), 256, 0, stream>>>(asrc, adst, dsrc, ddst, rp, deg, cs);

  // ---- group ranges ----
  hipMemsetAsync(gs, 0, (size_t)G_GROUPS * 4, stream);
  hipMemsetAsync(ge, 0, (size_t)G_GROUPS * 4, stream);
  group_bounds<<<ceil_div(N_ATOMS, 256), 256, 0, stream>>>(atom_batch, gs, ge, N_ATOMS);

  // ---- atom features ----
  gather_emb<<<ceil_div(N_ATOMS * 32, 256), 256, 0, stream>>>(emb, atom_x, bufA, N_ATOMS);
  hipMemsetAsync(x123, 0, (size_t)G_GROUPS * 256 * 4, stream);

  // ---- 3 GAT layers ----
  for (int L = 0; L < 3; ++L) {
    gemm_bf16<<<ceil_div(N_ATOMS, 256), 512, 0, stream>>>(bufA, Wsplit + (size_t)L * 32768, bufB, hs, hd,
                                                          attS[L], attD[L], N_ATOMS);
    edge_weights<<<ceil_div(N_ATOMS, 256), 256, 0, stream>>>(hs, hd, rp, cs, ew, wself, invz, N_ATOMS);
    gat_gather<<<N_ATOMS * 64 / 256, 256, 0, stream>>>(bufB, rp, cs, ew, wself, invz, gatB[L], poolP[L],
                                                       pn + L, bufA, N_ATOMS);
    pool_kernel<<<G_GROUPS, 256, 0, stream>>>(bufA, gs, ge, x123);
  }

  // ---- MLP + big-graph node features ----
  lin1_kernel<<<G_GROUPS, 128, 0, stream>>>(x123, lin1_W, lin1_b, xb1);
  xse_kernel<<<(N_BIG - G_GROUPS) * 64 / 256, 256, 0, stream>>>(emb, x_ids, nDrugPtr, nProtein, xb1);

  // ---- 2 GCN layers ----
  gemm_bf16<<<ceil_div(N_BIG, 256), 512, 0, stream>>>(xb1, Wsplit + (size_t)3 * 32768, bufB, nullptr, nullptr,
                                                      nullptr, nullptr, N_BIG);
  gcn_gather<<<N_BIG * 64 / 256, 256, 0, stream>>>(bufB, disB, rp + N_ATOMS, cs, gcn1_b, xb2, nullptr, N_BIG);
  gemm_bf16<<<ceil_div(N_BIG, 256), 512, 0, stream>>>(xb2, Wsplit + (size_t)4 * 32768, bufB, nullptr, nullptr,
                                                      nullptr, nullptr, N_BIG);
  gcn_gather<<<N_BIG * 64 / 256, 256, 0, stream>>>(bufB, disB, rp + N_ATOMS, cs, gcn2_b, nullptr, xbF, N_BIG);

  // ---- outputs ----
  out_gather<<<13000 * 64 / 256, 256, 0, stream>>>(xbF, drugNodes, seNodes, out);
}

// Round 6
// 602.537 us; speedup vs baseline: 3.1828x; 1.0202x over previous
//
#include <hip/hip_runtime.h>
#include <cfloat>
#include <cmath>

#define D 128
#define N_ATOMS 200000
#define E_ATOMS 800000
#define G_GROUPS 2000
#define N_BIG 7000
#define E_BIG 200000
#define N_ALL (N_ATOMS + N_BIG)
#define E_ALL (E_ATOMS + E_BIG)

static inline int ceil_div(int a, int b) { return (a + b - 1) / b; }

typedef __attribute__((ext_vector_type(8))) short bf16x8;
typedef __attribute__((ext_vector_type(4))) float f32x4;

__device__ inline short f2bf(float f) {
  unsigned u = __builtin_bit_cast(unsigned, f);
  u = (u + 0x7FFF + ((u >> 16) & 1)) >> 16;
  return (short)u;
}
__device__ inline float bf2f(short h) {
  unsigned u = ((unsigned)(unsigned short)h) << 16;
  return __builtin_bit_cast(float, u);
}
__device__ inline float bflo(unsigned p) { return __builtin_bit_cast(float, p << 16); }
__device__ inline float bfhi(unsigned p) { return __builtin_bit_cast(float, p & 0xFFFF0000u); }
__device__ inline unsigned bfpack(float x, float y) {
  return ((unsigned)(unsigned short)f2bf(x)) | (((unsigned)(unsigned short)f2bf(y)) << 16);
}
__device__ inline float leaky(float e) { return fmaxf(e, 0.2f * e); }
__device__ inline float fast_tanh(float x) {
  float cx = fminf(fmaxf(x, -15.f), 15.f);
  float t = __expf(2.f * cx);
  return (t - 1.f) * __frcp_rn(t + 1.f);
}

// ---------------- CSR build (both graphs merged) ----------------
__global__ void count_all(const int* __restrict__ adst, const int* __restrict__ ddst, int* __restrict__ deg) {
  int i = blockIdx.x * 256 + threadIdx.x;
  if (i < E_ATOMS)
    atomicAdd(&deg[adst[i]], 1);
  else if (i < E_ALL)
    atomicAdd(&deg[N_ATOMS + ddst[i - E_ATOMS]], 1);
}

__global__ void fill_all(const int* __restrict__ asrc, const int* __restrict__ adst,
                         const int* __restrict__ dsrc, const int* __restrict__ ddst,
                         const int* __restrict__ rp, int* __restrict__ fill, int* __restrict__ cs) {
  int i = blockIdx.x * 256 + threadIdx.x;
  if (i < E_ATOMS) {
    int idx = adst[i];
    int pos = rp[idx] + atomicAdd(&fill[idx], 1);
    cs[pos] = asrc[i];
  } else if (i < E_ALL) {
    int k = i - E_ATOMS;
    int idx = N_ATOMS + ddst[k];
    int pos = rp[idx] + atomicAdd(&fill[idx], 1);
    cs[pos] = dsrc[k];
  }
}

__global__ __launch_bounds__(256) void scan_phase1(const int* __restrict__ in, int* __restrict__ out,
                                                   int* __restrict__ bsums, int n) {
  __shared__ int lds[256];
  int t = threadIdx.x;
  int base = blockIdx.x * 1024;
  int v[4];
  int s = 0;
#pragma unroll
  for (int j = 0; j < 4; ++j) {
    int i = base + t * 4 + j;
    v[j] = (i < n) ? in[i] : 0;
    s += v[j];
  }
  lds[t] = s;
  __syncthreads();
  for (int off = 1; off < 256; off <<= 1) {
    int x = (t >= off) ? lds[t - off] : 0;
    __syncthreads();
    lds[t] += x;
    __syncthreads();
  }
  int excl = lds[t] - s;
  if (t == 255) bsums[blockIdx.x] = lds[255];
  int run = excl;
#pragma unroll
  for (int j = 0; j < 4; ++j) {
    int i = base + t * 4 + j;
    if (i < n) out[i] = run;
    run += v[j];
  }
}

__global__ __launch_bounds__(256) void scan_phase2(int* __restrict__ bsums, int* __restrict__ total_out, int nb) {
  __shared__ int lds[256];
  int t = threadIdx.x;
  int s = (t < nb) ? bsums[t] : 0;
  lds[t] = s;
  __syncthreads();
  for (int off = 1; off < 256; off <<= 1) {
    int x = (t >= off) ? lds[t - off] : 0;
    __syncthreads();
    lds[t] += x;
    __syncthreads();
  }
  if (t < nb) bsums[t] = lds[t] - s;
  if (t == 255) total_out[0] = lds[255];
}

__global__ void scan_phase3(int* __restrict__ out, const int* __restrict__ bsums, int n) {
  int i = blockIdx.x * 256 + threadIdx.x;
  if (i < n) out[i] += bsums[i >> 10];
}

// ---------------- prep: split 5 W's to swizzled bf16 hi/lo + inv pool-norms ----------------
__global__ __launch_bounds__(256) void prep_kernel(const float* __restrict__ W0, const float* __restrict__ W1,
                                                   const float* __restrict__ W2, const float* __restrict__ W3,
                                                   const float* __restrict__ W4, short* __restrict__ Wsplit,
                                                   const float* __restrict__ p0, const float* __restrict__ p1,
                                                   const float* __restrict__ p2, float* __restrict__ pn) {
  int b = blockIdx.x;
  if (b < 5) {
    const float* W = (b == 0) ? W0 : (b == 1) ? W1 : (b == 2) ? W2 : (b == 3) ? W3 : W4;
    short* dstH = Wsplit + (size_t)b * 32768;
    short* dstL = dstH + 16384;
    int t = threadIdx.x;
    int col = t & 127;
    int half = t >> 7;
#pragma unroll
    for (int kg = 0; kg < 8; ++kg) {
      int k0 = kg * 16 + half * 8;
      short vh[8], vl[8];
#pragma unroll
      for (int j = 0; j < 8; ++j) {
        float w = W[(k0 + j) * 128 + col];
        short hh = f2bf(w);
        vh[j] = hh;
        vl[j] = f2bf(w - bf2f(hh));
      }
      int byte_off = (col * 256 + k0 * 2) ^ ((col & 7) << 4);
      *(bf16x8*)((char*)dstH + byte_off) = *(bf16x8*)vh;
      *(bf16x8*)((char*)dstL + byte_off) = *(bf16x8*)vl;
    }
  } else {
    int t = threadIdx.x;
    int g = t >> 6, lane = t & 63;
    if (g < 3) {
      const float* p = (g == 0) ? p0 : (g == 1) ? p1 : p2;
      float2 v = ((const float2*)p)[lane];
      float s = v.x * v.x + v.y * v.y;
#pragma unroll
      for (int off = 32; off; off >>= 1) s += __shfl_xor(s, off);
      if (lane == 0) pn[g] = 1.f / sqrtf(s);
    }
  }
}

// ---------------- MFMA GEMM: H[M,128] = A[M,128](bf16) @ W (pre-split bf16 hi/lo) ----------
__global__ __launch_bounds__(512) void gemm_bf16(const short* __restrict__ A, const short* __restrict__ Wsp,
                                                 short* __restrict__ H, float* __restrict__ hs,
                                                 float* __restrict__ hd, const float* __restrict__ aS,
                                                 const float* __restrict__ aD, int M) {
  __shared__ short Wl[2 * 16384];  // hi at 0, lo at +16384 (transposed [col][k], XOR-swizzled)
  int t = threadIdx.x;
  {
    const uint4* src = (const uint4*)Wsp;
    uint4* dst = (uint4*)Wl;
#pragma unroll
    for (int i = 0; i < 8; ++i) dst[t + i * 512] = src[t + i * 512];
  }
  __syncthreads();
  int wave = t >> 6, lane = t & 63;
  int lr = lane & 15, lq = lane >> 4;
  int row0 = blockIdx.x * 256 + wave * 32;
  f32x4 acc[2][8];
#pragma unroll
  for (int rt = 0; rt < 2; ++rt)
#pragma unroll
    for (int ct = 0; ct < 8; ++ct) acc[rt][ct] = (f32x4){0.f, 0.f, 0.f, 0.f};

#pragma unroll
  for (int ks = 0; ks < 4; ++ks) {
    int k8 = ks * 32 + lq * 8;
    bf16x8 Af[2];
#pragma unroll
    for (int rt = 0; rt < 2; ++rt) {
      int row = row0 + rt * 16 + lr;
      if (row < M) {
        Af[rt] = *(const bf16x8*)(A + (size_t)row * D + k8);
      } else {
        Af[rt] = (bf16x8){0, 0, 0, 0, 0, 0, 0, 0};
      }
    }
#pragma unroll
    for (int ct = 0; ct < 8; ++ct) {
      int col = ct * 16 + lr;
      int byte_off = (col * 256 + k8 * 2) ^ ((col & 7) << 4);
      bf16x8 Bh = *(bf16x8*)((char*)Wl + byte_off);
      bf16x8 Bl = *(bf16x8*)((char*)Wl + 32768 + byte_off);
#pragma unroll
      for (int rt = 0; rt < 2; ++rt) {
        acc[rt][ct] = __builtin_amdgcn_mfma_f32_16x16x32_bf16(Af[rt], Bh, acc[rt][ct], 0, 0, 0);
        acc[rt][ct] = __builtin_amdgcn_mfma_f32_16x16x32_bf16(Af[rt], Bl, acc[rt][ct], 0, 0, 0);
      }
    }
  }
  // C/D layout: col = lane&15, row = (lane>>4)*4 + i
#pragma unroll
  for (int rt = 0; rt < 2; ++rt)
#pragma unroll
    for (int ct = 0; ct < 8; ++ct) {
      int col = ct * 16 + lr;
#pragma unroll
      for (int i = 0; i < 4; ++i) {
        int row = row0 + rt * 16 + lq * 4 + i;
        if (row < M) H[(size_t)row * D + col] = f2bf(acc[rt][ct][i]);
      }
    }
  if (aS) {
    float sA[8], sD[8];
#pragma unroll
    for (int ct = 0; ct < 8; ++ct) {
      sA[ct] = aS[ct * 16 + lr];
      sD[ct] = aD[ct * 16 + lr];
    }
#pragma unroll
    for (int rt = 0; rt < 2; ++rt)
#pragma unroll
      for (int i = 0; i < 4; ++i) {
        float ps = 0.f, pd = 0.f;
#pragma unroll
        for (int ct = 0; ct < 8; ++ct) {
          ps = fmaf(acc[rt][ct][i], sA[ct], ps);
          pd = fmaf(acc[rt][ct][i], sD[ct], pd);
        }
#pragma unroll
        for (int off = 1; off < 16; off <<= 1) {
          ps += __shfl_xor(ps, off);
          pd += __shfl_xor(pd, off);
        }
        int row = row0 + rt * 16 + lq * 4 + i;
        if (lr == 0 && row < M) {
          hs[row] = ps;
          hd[row] = pd;
        }
      }
  }
}

// ---------------- GAT edge weights -> extended {src, w} list (self appended) ----------------
__global__ void edge_weights(const float* __restrict__ hs, const float* __restrict__ hd,
                             const int* __restrict__ rp, const int* __restrict__ cs,
                             int2* __restrict__ cw, float* __restrict__ invz, int N) {
  int d = blockIdx.x * 256 + threadIdx.x;
  if (d >= N) return;
  int beg = rp[d], end = rp[d + 1];
  float hdd = hd[d];
  float es = leaky(hs[d] + hdd);
  float m = es;
  for (int i = beg; i < end; ++i) m = fmaxf(m, leaky(hs[cs[i]] + hdd));
  float z = __expf(es - m);
  int ob = beg + d;  // extended row start (each dst adds exactly one self entry)
  int2 se;
  se.x = d;
  se.y = __builtin_bit_cast(int, z);
  cw[ob + (end - beg)] = se;
  for (int i = beg; i < end; ++i) {
    float e = __expf(leaky(hs[cs[i]] + hdd) - m);
    int2 en;
    en.x = cs[i];
    en.y = __builtin_bit_cast(int, e);
    cw[ob + (i - beg)] = en;
    z += e;
  }
  invz[d] = 1.f / z;
}

// ---------------- GCN edge weights (feature-independent, built once) ----------------
__global__ void gcn_weights(const int* __restrict__ rpg, const int* __restrict__ cs,
                            const float* __restrict__ dis, int2* __restrict__ cwg, int N) {
  int d = blockIdx.x * 256 + threadIdx.x;
  if (d >= N) return;
  int beg = rpg[d], end = rpg[d + 1];  // absolute positions in merged cs
  float dd = dis[d];
  int ob = (beg - E_ATOMS) + d;
  for (int i = beg; i < end; ++i) {
    int s = cs[i];
    int2 en;
    en.x = s;
    en.y = __builtin_bit_cast(int, dis[s] * dd);
    cwg[ob + (i - beg)] = en;
  }
  int2 se;
  se.x = d;
  se.y = __builtin_bit_cast(int, dd * dd);
  cwg[ob + (end - beg)] = se;
}

// ---------------- GAT gather: wave per dst, 64 lanes x 2 channels, serial edges ------------
// All control data via scalar loads (wave-uniform d); H-row loads are saddr+lane*4.
__global__ __launch_bounds__(256) void gat_gather(const short* __restrict__ H, const int* __restrict__ rp,
                                                  const int2* __restrict__ cw, const float* __restrict__ invz,
                                                  const float* __restrict__ bias,
                                                  const float* __restrict__ poolP, const float* __restrict__ pnL,
                                                  short* __restrict__ Xout, int N) {
  int wid = (blockIdx.x * 256 + threadIdx.x) >> 6;
  int d = __builtin_amdgcn_readfirstlane(wid);
  if (d >= N) return;
  int lane = threadIdx.x & 63;
  int rb = rp[d], re = rp[d + 1];
  int beg = rb + d;
  int cnt = re - rb + 1;
  const unsigned* H2 = (const unsigned*)H;
  float ax = 0.f, ay = 0.f;
  int i = 0;
  for (; i + 2 <= cnt; i += 2) {
    int2 e0 = cw[beg + i];
    int2 e1 = cw[beg + i + 1];
    unsigned h0 = H2[(size_t)e0.x * 64 + lane];
    unsigned h1 = H2[(size_t)e1.x * 64 + lane];
    float w0 = __builtin_bit_cast(float, e0.y);
    float w1 = __builtin_bit_cast(float, e1.y);
    ax = fmaf(w0, bflo(h0), ax);
    ay = fmaf(w0, bfhi(h0), ay);
    ax = fmaf(w1, bflo(h1), ax);
    ay = fmaf(w1, bfhi(h1), ay);
  }
  if (i < cnt) {
    int2 e0 = cw[beg + i];
    unsigned h0 = H2[(size_t)e0.x * 64 + lane];
    float w0 = __builtin_bit_cast(float, e0.y);
    ax = fmaf(w0, bflo(h0), ax);
    ay = fmaf(w0, bfhi(h0), ay);
  }
  float iz = invz[d];
  float2 b2 = ((const float2*)bias)[lane];
  ax = fmaxf(fmaf(ax, iz, b2.x), 0.f);
  ay = fmaxf(fmaf(ay, iz, b2.y), 0.f);
  float2 p2 = ((const float2*)poolP)[lane];
  float dot = ax * p2.x + ay * p2.y;
#pragma unroll
  for (int off = 32; off; off >>= 1) dot += __shfl_xor(dot, off);
  float sc = fast_tanh(dot * pnL[0]);
  ((unsigned*)Xout)[(size_t)d * 64 + lane] = bfpack(ax * sc, ay * sc);
}

// ---------------- GCN gather: same structure; bf16 or fp32 out ----------------
__global__ __launch_bounds__(256) void gcn_gather(const short* __restrict__ Y, const int* __restrict__ rpg,
                                                  const int2* __restrict__ cwg, const float* __restrict__ b,
                                                  short* __restrict__ outB, float* __restrict__ outF, int N) {
  int wid = (blockIdx.x * 256 + threadIdx.x) >> 6;
  int d = __builtin_amdgcn_readfirstlane(wid);
  if (d >= N) return;
  int lane = threadIdx.x & 63;
  int rb = rpg[d], re = rpg[d + 1];
  int beg = (rb - E_ATOMS) + d;
  int cnt = re - rb + 1;
  const unsigned* Y2 = (const unsigned*)Y;
  float ax = 0.f, ay = 0.f;
  int i = 0;
  for (; i + 2 <= cnt; i += 2) {
    int2 e0 = cwg[beg + i];
    int2 e1 = cwg[beg + i + 1];
    unsigned h0 = Y2[(size_t)e0.x * 64 + lane];
    unsigned h1 = Y2[(size_t)e1.x * 64 + lane];
    float w0 = __builtin_bit_cast(float, e0.y);
    float w1 = __builtin_bit_cast(float, e1.y);
    ax = fmaf(w0, bflo(h0), ax);
    ay = fmaf(w0, bfhi(h0), ay);
    ax = fmaf(w1, bflo(h1), ax);
    ay = fmaf(w1, bfhi(h1), ay);
  }
  if (i < cnt) {
    int2 e0 = cwg[beg + i];
    unsigned h0 = Y2[(size_t)e0.x * 64 + lane];
    float w0 = __builtin_bit_cast(float, e0.y);
    ax = fmaf(w0, bflo(h0), ax);
    ay = fmaf(w0, bfhi(h0), ay);
  }
  float2 b2 = ((const float2*)b)[lane];
  float ox = fmaxf(ax + b2.x, 0.f);
  float oy = fmaxf(ay + b2.y, 0.f);
  if (outF)
    ((float2*)outF)[(size_t)d * 64 + lane] = make_float2(ox, oy);
  else
    ((unsigned*)outB)[(size_t)d * 64 + lane] = bfpack(ox, oy);
}

__global__ void group_bounds(const int* __restrict__ batch, int* __restrict__ gs, int* __restrict__ ge, int n) {
  int i = blockIdx.x * 256 + threadIdx.x;
  if (i >= n) return;
  int b = batch[i];
  if (i == 0 || batch[i - 1] != b) gs[b] = i;
  if (i == n - 1 || batch[i + 1] != b) ge[b] = i + 1;
}

// per-group max & mean; 4 waves split rows, LDS combine
__global__ __launch_bounds__(256) void pool_kernel(const short* __restrict__ X, const int* __restrict__ gs,
                                                   const int* __restrict__ ge, float* __restrict__ x123) {
  __shared__ float2 mxs[4][64];
  __shared__ float2 sms[4][64];
  int g = blockIdx.x;
  int wv = threadIdx.x >> 6;
  int p = threadIdx.x & 63;
  int beg = gs[g], end = ge[g];
  int cnt = end - beg;
  const unsigned* X2 = (const unsigned*)X;
  float mx0 = -FLT_MAX, mx1 = -FLT_MAX, sm0 = 0.f, sm1 = 0.f;
  for (int i = beg + wv; i < end; i += 4) {
    unsigned v = X2[(size_t)i * 64 + p];
    float a = bflo(v), b = bfhi(v);
    mx0 = fmaxf(mx0, a);
    mx1 = fmaxf(mx1, b);
    sm0 += a;
    sm1 += b;
  }
  mxs[wv][p] = make_float2(mx0, mx1);
  sms[wv][p] = make_float2(sm0, sm1);
  __syncthreads();
  if (threadIdx.x < 64 && cnt > 0) {
#pragma unroll
    for (int k = 1; k < 4; ++k) {
      float2 m2 = mxs[k][p], s2 = sms[k][p];
      mx0 = fmaxf(mx0, m2.x);
      mx1 = fmaxf(mx1, m2.y);
      sm0 += s2.x;
      sm1 += s2.y;
    }
    float inv = 1.f / (float)cnt;
    float* xg = x123 + (size_t)g * 256;
    xg[2 * p] += mx0;
    xg[2 * p + 1] += mx1;
    xg[128 + 2 * p] += sm0 * inv;
    xg[128 + 2 * p + 1] += sm1 * inv;
  }
}

// xDP = relu(x123 @ lin1_W + lin1_b), bf16 out
__global__ __launch_bounds__(128) void lin1_kernel(const float* __restrict__ x123, const float* __restrict__ W,
                                                   const float* __restrict__ b, short* __restrict__ xb) {
  __shared__ float row[256];
  int g = blockIdx.x;
  int c = threadIdx.x;
  row[c] = x123[(size_t)g * 256 + c];
  row[c + 128] = x123[(size_t)g * 256 + 128 + c];
  __syncthreads();
  float acc = b[c];
#pragma unroll 8
  for (int k = 0; k < 256; ++k) acc = fmaf(row[k], W[k * 128 + c], acc);
  xb[(size_t)g * D + c] = f2bf(fmaxf(acc, 0.f));
}

__global__ void xse_kernel(const float* __restrict__ emb, const int* __restrict__ x_ids,
                           const int* __restrict__ nDrugPtr, int nProtein, short* __restrict__ xb) {
  int idx = blockIdx.x * 256 + threadIdx.x;
  int r = idx >> 6, lane = idx & 63;
  int off = nDrugPtr[0] + nProtein;
  int id = x_ids[off + r];
  float2 v = ((const float2*)(emb + (size_t)id * D))[lane];
  ((unsigned*)xb)[(size_t)(G_GROUPS + r) * 64 + lane] = bfpack(v.x, v.y);
}

__global__ void dis_kernel(const int* __restrict__ deg, float* __restrict__ dis, int n) {
  int i = blockIdx.x * 256 + threadIdx.x;
  if (i < n) dis[i] = 1.f / sqrtf((float)(deg[N_ATOMS + i] + 1));
}

// 2 nodes per wave, float4 loads
__global__ void gather_emb(const float* __restrict__ emb, const int* __restrict__ ids, short* __restrict__ out,
                           int n) {
  int idx = blockIdx.x * 256 + threadIdx.x;
  int node = idx >> 5, lane = idx & 31;
  if (node >= n) return;
  float4 v = ((const float4*)(emb + (size_t)ids[node] * D))[lane];
  uint2 o;
  o.x = bfpack(v.x, v.y);
  o.y = bfpack(v.z, v.w);
  ((uint2*)out)[(size_t)node * 32 + lane] = o;
}

__global__ void out_gather(const float* __restrict__ xb, const int* __restrict__ dn, const int* __restrict__ sn,
                           float* __restrict__ out) {
  int idx = blockIdx.x * 256 + threadIdx.x;
  int r = idx >> 6, lane = idx & 63;
  int s = (r < 1000) ? dn[r] : (r < 6000) ? sn[r - 1000] : (r - 6000);
  ((float2*)out)[(size_t)idx] = ((const float2*)(xb + (size_t)s * D))[lane];
}

extern "C" void kernel_launch(void* const* d_in, const int* in_sizes, int n_in, void* d_out, int out_size,
                              void* d_ws, size_t ws_size, hipStream_t stream) {
  const int* x_ids = (const int*)d_in[0];
  const int* drugE = (const int*)d_in[1];
  const int* drugNodes = (const int*)d_in[3];
  const int* seNodes = (const int*)d_in[4];
  int nProtein = in_sizes[5];
  const int* atom_x = (const int*)d_in[7];
  const int* atomE = (const int*)d_in[8];
  const int* atom_batch = (const int*)d_in[9];
  const int* nDrugPtr = (const int*)d_in[10];
  const float* emb = (const float*)d_in[11];
  const float* gatW[3] = {(const float*)d_in[12], (const float*)d_in[17], (const float*)d_in[22]};
  const float* attS[3] = {(const float*)d_in[13], (const float*)d_in[18], (const float*)d_in[23]};
  const float* attD[3] = {(const float*)d_in[14], (const float*)d_in[19], (const float*)d_in[24]};
  const float* gatB[3] = {(const float*)d_in[15], (const float*)d_in[20], (const float*)d_in[25]};
  const float* poolP[3] = {(const float*)d_in[16], (const float*)d_in[21], (const float*)d_in[26]};
  const float* lin1_W = (const float*)d_in[27];
  const float* lin1_b = (const float*)d_in[28];
  const float* gcn1_W = (const float*)d_in[29];
  const float* gcn1_b = (const float*)d_in[30];
  const float* gcn2_W = (const float*)d_in[31];
  const float* gcn2_b = (const float*)d_in[32];
  float* out = (float*)d_out;
  (void)n_in; (void)out_size; (void)ws_size;

  char* ws = (char*)d_ws;
  size_t off = 0;
  auto alloc = [&](size_t bytes) -> char* {
    char* p = ws + off;
    off += (bytes + 255) & ~(size_t)255;
    return p;
  };
  short* bufA = (short*)alloc((size_t)N_ATOMS * D * 2);  // xa (bf16)
  short* bufB = (short*)alloc((size_t)N_ATOMS * D * 2);  // h  (bf16)
  float* hs = (float*)alloc((size_t)N_ATOMS * 4);
  float* hd = (float*)alloc((size_t)N_ATOMS * 4);
  int2* cw = (int2*)alloc((size_t)(E_ATOMS + N_ATOMS) * 8);
  int2* cwg = (int2*)alloc((size_t)(E_BIG + N_BIG) * 8);
  float* invz = (float*)alloc((size_t)N_ATOMS * 4);
  float* x123 = (float*)alloc((size_t)G_GROUPS * 256 * 4);
  short* xb1 = (short*)alloc((size_t)N_BIG * D * 2);
  short* xb2 = (short*)alloc((size_t)N_BIG * D * 2);
  float* xbF = (float*)alloc((size_t)N_BIG * D * 4);
  short* Wsplit = (short*)alloc((size_t)5 * 32768 * 2);
  int* rp = (int*)alloc((size_t)(N_ALL + 1) * 4);
  int* cs = (int*)alloc((size_t)E_ALL * 4);
  int* deg = (int*)alloc((size_t)N_ALL * 4);
  float* disB = (float*)alloc((size_t)N_BIG * 4);
  int* gs = (int*)alloc((size_t)G_GROUPS * 4);
  int* ge = (int*)alloc((size_t)G_GROUPS * 4);
  int* bsums = (int*)alloc(256 * 4);
  float* pn = (float*)alloc(256);

  const int* asrc = atomE;
  const int* adst = atomE + E_ATOMS;
  const int* dsrc = drugE;
  const int* ddst = drugE + E_BIG;

  // ---- prep (weight split + pool norms) ----
  prep_kernel<<<6, 256, 0, stream>>>(gatW[0], gatW[1], gatW[2], gcn1_W, gcn2_W, Wsplit, poolP[0], poolP[1],
                                     poolP[2], pn);

  // ---- merged CSR ----
  hipMemsetAsync(deg, 0, (size_t)N_ALL * 4, stream);
  count_all<<<ceil_div(E_ALL, 256), 256, 0, stream>>>(adst, ddst, deg);
  scan_phase1<<<ceil_div(N_ALL, 1024), 256, 0, stream>>>(deg, rp, bsums, N_ALL);
  scan_phase2<<<1, 256, 0, stream>>>(bsums, rp + N_ALL, ceil_div(N_ALL, 1024));
  scan_phase3<<<ceil_div(N_ALL, 256), 256, 0, stream>>>(rp, bsums, N_ALL);
  dis_kernel<<<ceil_div(N_BIG, 256), 256, 0, stream>>>(deg, disB, N_BIG);
  hipMemsetAsync(deg, 0, (size_t)N_ALL * 4, stream);
  fill_all<<<ceil_div(E_ALL, 256), 256, 0, stream>>>(asrc, adst, dsrc, ddst, rp, deg, cs);
  gcn_weights<<<ceil_div(N_BIG, 256), 256, 0, stream>>>(rp + N_ATOMS, cs, disB, cwg, N_BIG);

  // ---- group ranges ----
  hipMemsetAsync(gs, 0, (size_t)G_GROUPS * 4, stream);
  hipMemsetAsync(ge, 0, (size_t)G_GROUPS * 4, stream);
  group_bounds<<<ceil_div(N_ATOMS, 256), 256, 0, stream>>>(atom_batch, gs, ge, N_ATOMS);

  // ---- atom features ----
  gather_emb<<<ceil_div(N_ATOMS * 32, 256), 256, 0, stream>>>(emb, atom_x, bufA, N_ATOMS);
  hipMemsetAsync(x123, 0, (size_t)G_GROUPS * 256 * 4, stream);

  // ---- 3 GAT layers ----
  for (int L = 0; L < 3; ++L) {
    gemm_bf16<<<ceil_div(N_ATOMS, 256), 512, 0, stream>>>(bufA, Wsplit + (size_t)L * 32768, bufB, hs, hd,
                                                          attS[L], attD[L], N_ATOMS);
    edge_weights<<<ceil_div(N_ATOMS, 256), 256, 0, stream>>>(hs, hd, rp, cs, cw, invz, N_ATOMS);
    gat_gather<<<N_ATOMS * 64 / 256, 256, 0, stream>>>(bufB, rp, cw, invz, gatB[L], poolP[L], pn + L, bufA,
                                                       N_ATOMS);
    pool_kernel<<<G_GROUPS, 256, 0, stream>>>(bufA, gs, ge, x123);
  }

  // ---- MLP + big-graph node features ----
  lin1_kernel<<<G_GROUPS, 128, 0, stream>>>(x123, lin1_W, lin1_b, xb1);
  xse_kernel<<<(N_BIG - G_GROUPS) * 64 / 256, 256, 0, stream>>>(emb, x_ids, nDrugPtr, nProtein, xb1);

  // ---- 2 GCN layers ----
  gemm_bf16<<<ceil_div(N_BIG, 256), 512, 0, stream>>>(xb1, Wsplit + (size_t)3 * 32768, bufB, nullptr, nullptr,
                                                      nullptr, nullptr, N_BIG);
  gcn_gather<<<N_BIG * 64 / 256, 256, 0, stream>>>(bufB, rp + N_ATOMS, cwg, gcn1_b, xb2, nullptr, N_BIG);
  gemm_bf16<<<ceil_div(N_BIG, 256), 512, 0, stream>>>(xb2, Wsplit + (size_t)4 * 32768, bufB, nullptr, nullptr,
                                                      nullptr, nullptr, N_BIG);
  gcn_gather<<<N_BIG * 64 / 256, 256, 0, stream>>>(bufB, rp + N_ATOMS, cwg, gcn2_b, nullptr, xbF, N_BIG);

  // ---- outputs ----
  out_gather<<<13000 * 64 / 256, 256, 0, stream>>>(xbF, drugNodes, seNodes, out);
}